// Round 7
// baseline (4346.004 us; speedup 1.0000x reference)
//
#include <hip/hip_runtime.h>
#include <math.h>

#define N_FEAT 8192
#define DIM    768
#define B_H    4096
#define P_PK   2048
#define C_CLS  256
#define KNN    20
#define MCAND  32   // candidate margin for exact re-rank

// output layout (all float32, concatenated in reference return order)
#define OUT_DENS_OFF  (B_H * C_CLS)                 // 1048576
#define OUT_KNN_OFF   (OUT_DENS_OFF + N_FEAT)       // 1056768
#define OUT_MASK_OFF  (OUT_KNN_OFF + N_FEAT * KNN)  // 1220608

// ---------------------------------------------------------------------------
// Truth-rounded f32 row norm: n32 = fl32( sqrt_f64( sum_f64(x^2) ) ).
// One wave per row. Also emits 1/n32 for the fast candidate GEMM.
// ---------------------------------------------------------------------------
__global__ __launch_bounds__(256) void norm64_kernel(const float* __restrict__ X,
    float* __restrict__ nrm, float* __restrict__ rn, int rows) {
  int w    = (int)((blockIdx.x * blockDim.x + threadIdx.x) >> 6);
  int lane = threadIdx.x & 63;
  if (w >= rows) return;
  const float* x = X + (size_t)w * DIM;
  double s = 0.0;
#pragma unroll
  for (int k = 0; k < 12; ++k) {
    float v = x[lane + 64 * k];
    s += (double)v * (double)v;
  }
#pragma unroll
  for (int off = 32; off; off >>= 1) s += __shfl_xor(s, off);
  if (lane == 0) {
    float n32 = (float)sqrt(s);          // truth-rounded f32 norm
    nrm[w] = n32;
    rn[w]  = 1.0f / n32;
  }
}

// ---------------------------------------------------------------------------
// Fast f32 candidate GEMM with streaming top-MCAND list (self excluded).
// Candidates only; exact ranking happens in refine. (unchanged since r1)
// ---------------------------------------------------------------------------
__global__ __launch_bounds__(512) void sim_topk_kernel(const float* __restrict__ F,
    const float* __restrict__ rn, int* __restrict__ cand) {
  __shared__ __align__(16) float As[32][36];
  __shared__ __align__(16) float Bs[32][132];
  __shared__ __align__(16) float simb[32][130];
  __shared__ float topv[32][MCAND];
  __shared__ int   topi[32][MCAND];

  const int t  = threadIdx.x;
  const int ib = blockIdx.x * 32;
  const int tx = t & 63;
  const int ry = t >> 6;
  const int ar  = t >> 4;
  const int akk = (t & 15) * 2;
  const int br  = t >> 2;
  const int bkk = (t & 3) * 8;

  for (int i = t; i < 32 * MCAND; i += 512) {
    ((float*)topv)[i] = -1e30f;
    ((int*)topi)[i]   = 0;
  }
  const float arn = rn[ib + ar];
  __syncthreads();

  for (int ct = 0; ct < 64; ++ct) {
    const int jb = ct * 128;
    const float brn = rn[jb + br];
    float acc[4][2];
#pragma unroll
    for (int r = 0; r < 4; ++r) { acc[r][0] = 0.f; acc[r][1] = 0.f; }

    for (int kc = 0; kc < 24; ++kc) {
      const int kb = kc * 32;
      __syncthreads();
      {
        float2 v = *(const float2*)(F + (size_t)(ib + ar) * DIM + kb + akk);
        As[akk][ar]     = v.x * arn;
        As[akk + 1][ar] = v.y * arn;
      }
      {
        const float* src = F + (size_t)(jb + br) * DIM + kb + bkk;
        float4 v0 = *(const float4*)(src);
        float4 v1 = *(const float4*)(src + 4);
        Bs[bkk + 0][br] = v0.x * brn;
        Bs[bkk + 1][br] = v0.y * brn;
        Bs[bkk + 2][br] = v0.z * brn;
        Bs[bkk + 3][br] = v0.w * brn;
        Bs[bkk + 4][br] = v1.x * brn;
        Bs[bkk + 5][br] = v1.y * brn;
        Bs[bkk + 6][br] = v1.z * brn;
        Bs[bkk + 7][br] = v1.w * brn;
      }
      __syncthreads();
#pragma unroll
      for (int k = 0; k < 32; ++k) {
        float4 a = *(const float4*)&As[k][4 * ry];
        float2 b = *(const float2*)&Bs[k][2 * tx];
        acc[0][0] += a.x * b.x; acc[0][1] += a.x * b.y;
        acc[1][0] += a.y * b.x; acc[1][1] += a.y * b.y;
        acc[2][0] += a.z * b.x; acc[2][1] += a.z * b.y;
        acc[3][0] += a.w * b.x; acc[3][1] += a.w * b.y;
      }
    }
#pragma unroll
    for (int r = 0; r < 4; ++r) {
      *(float2*)&simb[4 * ry + r][2 * tx] = make_float2(acc[r][0], acc[r][1]);
    }
    for (int rr = 0; rr < 4; ++rr) {
      const int r  = 4 * ry + rr;
      const int ig = ib + r;
      float v0 = simb[r][tx];
      float v1 = simb[r][64 + tx];
      if (jb + tx == ig)      v0 = -3.0e38f;
      if (jb + 64 + tx == ig) v1 = -3.0e38f;
      float cmin = topv[r][MCAND - 1];
      unsigned long long m0 = __ballot(v0 > cmin);
      unsigned long long m1 = __ballot(v1 > cmin);
      while (m0 | m1) {
        float v; int j;
        if (m0) {
          int l = __ffsll(m0) - 1; m0 &= (m0 - 1);
          v = __shfl(v0, l); j = jb + l;
        } else {
          int l = __ffsll(m1) - 1; m1 &= (m1 - 1);
          v = __shfl(v1, l); j = jb + 64 + l;
        }
        if (v > topv[r][MCAND - 1]) {
          int pos = MCAND - 1;
          while (pos > 0 && topv[r][pos - 1] < v) {
            topv[r][pos] = topv[r][pos - 1];
            topi[r][pos] = topi[r][pos - 1];
            --pos;
          }
          topv[r][pos] = v;
          topi[r][pos] = j;
        }
      }
    }
  }
  for (int rr = 0; rr < 4; ++rr) {
    const int r  = 4 * ry + rr;
    const int ig = ib + r;
    if (tx < MCAND) cand[(size_t)ig * MCAND + tx] = topi[r][tx];
  }
}

// ---------------------------------------------------------------------------
// Re-rank by fl32(truth): fn = fl32(F/n32) (materialized-f32 fn like ref),
// dot accumulated in f64 (f32xf32 exact), rounded to f32 at the end.
// Ties in f32 broken HIGH-index-first (reversed-argsort shim semantics).
// One block = 8 rows x 32 candidate-threads; each thread = one full dot.
// ---------------------------------------------------------------------------
__global__ __launch_bounds__(256) void refine_kernel(const float* __restrict__ F,
    const float* __restrict__ nrm, const int* __restrict__ cand,
    float* __restrict__ dens, float* __restrict__ knnf) {
#pragma clang fp contract(off)
  const int t  = threadIdx.x;
  const int i0 = blockIdx.x * 8;
  __shared__ __align__(16) float fni[8][DIM];   // 24 KB
  __shared__ float svals[8][MCAND];
  __shared__ int   sidx[8][MCAND];
  __shared__ float ssorted[8][MCAND];

  // stage fn_i rows: bit-exact f32 division by the truth-rounded f32 norm
  for (int r = 0; r < 8; ++r) {
    const float ni = nrm[i0 + r];
    const float* src = F + (size_t)(i0 + r) * DIM;
    for (int d = t; d < DIM; d += 256) fni[r][d] = src[d] / ni;
  }
  __syncthreads();

  const int row = t >> 5;       // 0..7
  const int c   = t & 31;       // candidate slot
  const int ig  = i0 + row;
  const int j   = cand[(size_t)ig * MCAND + c];
  const float nj = nrm[j];
  const float* fj = F + (size_t)j * DIM;
  const float* a  = fni[row];

  double acc = 0.0;
#pragma unroll 4
  for (int kq = 0; kq < 192; ++kq) {
    float4 bv = *(const float4*)(fj + 4 * kq);
    float4 av = *(const float4*)(a + 4 * kq);
    float b0 = bv.x / nj, b1 = bv.y / nj, b2 = bv.z / nj, b3 = bv.w / nj;
    acc += (double)av.x * (double)b0;
    acc += (double)av.y * (double)b1;
    acc += (double)av.z * (double)b2;
    acc += (double)av.w * (double)b3;
  }
  const float s = (float)acc;   // fl32(truth)

  svals[row][c] = s;
  sidx[row][c]  = j;
  __syncthreads();

  // rank among the 32 candidates: descending by f32 value,
  // exact f32 ties broken HIGHER index first
  int rank = 0;
  for (int k = 0; k < MCAND; ++k) {
    float vk = svals[row][k]; int jk = sidx[row][k];
    rank += (vk > s || (vk == s && jk > j)) ? 1 : 0;
  }
  if (rank < KNN) knnf[(size_t)ig * KNN + rank] = (float)j;
  ssorted[row][rank] = s;
  __syncthreads();

  // numpy pairwise mean over the 20 sorted-desc f32 values
  if (c == 0) {
    float rr[8];
#pragma unroll
    for (int q = 0; q < 8; ++q) rr[q] = ssorted[row][q];
#pragma unroll
    for (int q = 0; q < 8; ++q) rr[q] = rr[q] + ssorted[row][8 + q];
    float res = ((rr[0] + rr[1]) + (rr[2] + rr[3])) + ((rr[4] + rr[5]) + (rr[6] + rr[7]));
    res = res + ssorted[row][16];
    res = res + ssorted[row][17];
    res = res + ssorted[row][18];
    res = res + ssorted[row][19];
    dens[ig] = res / 20.0f;
  }
}

// ---------------------------------------------------------------------------
// peak_mask[i] = all(dens[i] > dens[knn[i][k]])  (f32 comparisons)
// ---------------------------------------------------------------------------
__global__ __launch_bounds__(256) void peak_kernel(const float* __restrict__ dens,
    const float* __restrict__ knnf, float* __restrict__ mask) {
  int i = blockIdx.x * 256 + threadIdx.x;
  if (i >= N_FEAT) return;
  float di = dens[i];
  int ok = 1;
#pragma unroll
  for (int k = 0; k < KNN; ++k) {
    int j = (int)knnf[(size_t)i * KNN + k];
    ok &= (di > dens[j]) ? 1 : 0;
  }
  mask[i] = ok ? 1.0f : 0.0f;
}

// ---------------------------------------------------------------------------
// preds = softmax(hn @ pn^T / tau) @ one_hot(labels)   (unchanged, passing)
// ---------------------------------------------------------------------------
__global__ __launch_bounds__(256) void preds_kernel(const float* __restrict__ H,
    const float* __restrict__ Pk, const int* __restrict__ labels,
    const float* __restrict__ rnh, const float* __restrict__ rnp,
    float* __restrict__ outp) {
  __shared__ __align__(16) float Hs[32][20];
  __shared__ __align__(16) float Ps[32][130];
  __shared__ float accc[16][C_CLS];

  const int t  = threadIdx.x;
  const int hb = blockIdx.x * 16;
  const int tx = t & 63;
  const int ry = t >> 6;
  const int hr  = t >> 4;
  const int hkk = (t & 15) * 2;
  const int pr  = t >> 1;
  const int pkk = (t & 1) * 16;
  const float hrn = rnh[hb + hr];

  for (int i = t; i < 16 * C_CLS; i += 256) ((float*)accc)[i] = 0.f;

  float m[4]    = {-3e38f, -3e38f, -3e38f, -3e38f};
  float ssum[4] = {0.f, 0.f, 0.f, 0.f};
  __syncthreads();

  for (int pt = 0; pt < 16; ++pt) {
    const int pb = pt * 128;
    const float prn = rnp[pb + pr];
    float acc[4][2];
#pragma unroll
    for (int r = 0; r < 4; ++r) { acc[r][0] = 0.f; acc[r][1] = 0.f; }

    for (int kc = 0; kc < 24; ++kc) {
      const int kb = kc * 32;
      __syncthreads();
      {
        float2 v = *(const float2*)(H + (size_t)(hb + hr) * DIM + kb + hkk);
        Hs[hkk][hr]     = v.x * hrn;
        Hs[hkk + 1][hr] = v.y * hrn;
      }
      {
        const float* src = Pk + (size_t)(pb + pr) * DIM + kb + pkk;
        float4 v0 = *(const float4*)(src);
        float4 v1 = *(const float4*)(src + 4);
        float4 v2 = *(const float4*)(src + 8);
        float4 v3 = *(const float4*)(src + 12);
        Ps[pkk +  0][pr] = v0.x * prn;  Ps[pkk +  1][pr] = v0.y * prn;
        Ps[pkk +  2][pr] = v0.z * prn;  Ps[pkk +  3][pr] = v0.w * prn;
        Ps[pkk +  4][pr] = v1.x * prn;  Ps[pkk +  5][pr] = v1.y * prn;
        Ps[pkk +  6][pr] = v1.z * prn;  Ps[pkk +  7][pr] = v1.w * prn;
        Ps[pkk +  8][pr] = v2.x * prn;  Ps[pkk +  9][pr] = v2.y * prn;
        Ps[pkk + 10][pr] = v2.z * prn;  Ps[pkk + 11][pr] = v2.w * prn;
        Ps[pkk + 12][pr] = v3.x * prn;  Ps[pkk + 13][pr] = v3.y * prn;
        Ps[pkk + 14][pr] = v3.z * prn;  Ps[pkk + 15][pr] = v3.w * prn;
      }
      __syncthreads();
#pragma unroll
      for (int k = 0; k < 32; ++k) {
        float4 a = *(const float4*)&Hs[k][4 * ry];
        float2 b = *(const float2*)&Ps[k][2 * tx];
        acc[0][0] += a.x * b.x; acc[0][1] += a.x * b.y;
        acc[1][0] += a.y * b.x; acc[1][1] += a.y * b.y;
        acc[2][0] += a.z * b.x; acc[2][1] += a.z * b.y;
        acc[3][0] += a.w * b.x; acc[3][1] += a.w * b.y;
      }
    }
    const int lab0 = labels[pb + 2 * tx];
    const int lab1 = labels[pb + 2 * tx + 1];
#pragma unroll
    for (int rr = 0; rr < 4; ++rr) {
      float l0 = acc[rr][0] / 0.07f;
      float l1 = acc[rr][1] / 0.07f;
      float tm = fmaxf(l0, l1);
#pragma unroll
      for (int off = 32; off; off >>= 1) tm = fmaxf(tm, __shfl_xor(tm, off));
      float mn = fmaxf(m[rr], tm);
      float sc = expf(m[rr] - mn);
      const int row = 4 * ry + rr;
#pragma unroll
      for (int q = 0; q < 4; ++q) accc[row][tx + 64 * q] *= sc;
      float e0 = expf(l0 - mn);
      float e1 = expf(l1 - mn);
      float es = e0 + e1;
#pragma unroll
      for (int off = 32; off; off >>= 1) es += __shfl_xor(es, off);
      ssum[rr] = ssum[rr] * sc + es;
      m[rr] = mn;
      atomicAdd(&accc[row][lab0], e0);
      atomicAdd(&accc[row][lab1], e1);
    }
  }
#pragma unroll
  for (int rr = 0; rr < 4; ++rr) {
    const int row = 4 * ry + rr;
    float inv = 1.0f / ssum[rr];
#pragma unroll
    for (int q = 0; q < 4; ++q) {
      outp[(size_t)(hb + row) * C_CLS + tx + 64 * q] = accc[row][tx + 64 * q] * inv;
    }
  }
}

// ---------------------------------------------------------------------------
extern "C" void kernel_launch(void* const* d_in, const int* in_sizes, int n_in,
                              void* d_out, int out_size, void* d_ws, size_t ws_size,
                              hipStream_t stream) {
  (void)in_sizes; (void)n_in; (void)out_size; (void)ws_size;
  const float* F      = (const float*)d_in[0];
  const float* H      = (const float*)d_in[1];
  const float* Pk     = (const float*)d_in[2];
  const int*   labels = (const int*)d_in[3];
  float* out = (float*)d_out;

  float* ws   = (float*)d_ws;
  float* nrmF = ws;                    // 8192 (truth-rounded f32 norms)
  float* rnF  = nrmF + N_FEAT;         // 8192 (fast reciprocals)
  float* nrmH = rnF + N_FEAT;          // 4096
  float* rnH  = nrmH + B_H;            // 4096
  float* nrmP = rnH + B_H;             // 2048
  float* rnP  = nrmP + P_PK;           // 2048
  int*   cand = (int*)(rnP + P_PK);    // 8192*32 int

  norm64_kernel<<<N_FEAT / 4, 256, 0, stream>>>(F, nrmF, rnF, N_FEAT);
  norm64_kernel<<<B_H / 4,  256, 0, stream>>>(H, nrmH, rnH, B_H);
  norm64_kernel<<<P_PK / 4, 256, 0, stream>>>(Pk, nrmP, rnP, P_PK);

  sim_topk_kernel<<<N_FEAT / 32, 512, 0, stream>>>(F, rnF, cand);

  refine_kernel<<<N_FEAT / 8, 256, 0, stream>>>(F, nrmF, cand,
      out + OUT_DENS_OFF, out + OUT_KNN_OFF);

  peak_kernel<<<N_FEAT / 256, 256, 0, stream>>>(out + OUT_DENS_OFF,
      out + OUT_KNN_OFF, out + OUT_MASK_OFF);

  preds_kernel<<<B_H / 16, 256, 0, stream>>>(H, Pk, labels, rnH, rnP, out);
}

// Round 8
// 4319.275 us; speedup vs baseline: 1.0062x; 1.0062x over previous
//
#include <hip/hip_runtime.h>
#include <math.h>

#define N_FEAT 8192
#define DIM    768
#define B_H    4096
#define P_PK   2048
#define C_CLS  256
#define KNN    20
#define MCAND  32   // candidate margin for exact re-rank

// output layout (all float32, concatenated in reference return order)
#define OUT_DENS_OFF  (B_H * C_CLS)                 // 1048576
#define OUT_KNN_OFF   (OUT_DENS_OFF + N_FEAT)       // 1056768
#define OUT_MASK_OFF  (OUT_KNN_OFF + N_FEAT * KNN)  // 1220608

// ---------------------------------------------------------------------------
// Truth-rounded f32 row norm: n32 = fl32( sqrt_f64( sum_f64(x^2) ) ).
// One wave per row. Also emits 1/n32 for the fast candidate GEMM.
// ---------------------------------------------------------------------------
__global__ __launch_bounds__(256) void norm64_kernel(const float* __restrict__ X,
    float* __restrict__ nrm, float* __restrict__ rn, int rows) {
  int w    = (int)((blockIdx.x * blockDim.x + threadIdx.x) >> 6);
  int lane = threadIdx.x & 63;
  if (w >= rows) return;
  const float* x = X + (size_t)w * DIM;
  double s = 0.0;
#pragma unroll
  for (int k = 0; k < 12; ++k) {
    float v = x[lane + 64 * k];
    s += (double)v * (double)v;
  }
#pragma unroll
  for (int off = 32; off; off >>= 1) s += __shfl_xor(s, off);
  if (lane == 0) {
    float n32 = (float)sqrt(s);          // truth-rounded f32 norm
    nrm[w] = n32;
    rn[w]  = 1.0f / n32;
  }
}

// ---------------------------------------------------------------------------
// Fast f32 candidate GEMM with streaming top-MCAND list (self excluded).
// Candidates only; exact ranking happens in refine. (unchanged since r1)
// ---------------------------------------------------------------------------
__global__ __launch_bounds__(512) void sim_topk_kernel(const float* __restrict__ F,
    const float* __restrict__ rn, int* __restrict__ cand) {
  __shared__ __align__(16) float As[32][36];
  __shared__ __align__(16) float Bs[32][132];
  __shared__ __align__(16) float simb[32][130];
  __shared__ float topv[32][MCAND];
  __shared__ int   topi[32][MCAND];

  const int t  = threadIdx.x;
  const int ib = blockIdx.x * 32;
  const int tx = t & 63;
  const int ry = t >> 6;
  const int ar  = t >> 4;
  const int akk = (t & 15) * 2;
  const int br  = t >> 2;
  const int bkk = (t & 3) * 8;

  for (int i = t; i < 32 * MCAND; i += 512) {
    ((float*)topv)[i] = -1e30f;
    ((int*)topi)[i]   = 0;
  }
  const float arn = rn[ib + ar];
  __syncthreads();

  for (int ct = 0; ct < 64; ++ct) {
    const int jb = ct * 128;
    const float brn = rn[jb + br];
    float acc[4][2];
#pragma unroll
    for (int r = 0; r < 4; ++r) { acc[r][0] = 0.f; acc[r][1] = 0.f; }

    for (int kc = 0; kc < 24; ++kc) {
      const int kb = kc * 32;
      __syncthreads();
      {
        float2 v = *(const float2*)(F + (size_t)(ib + ar) * DIM + kb + akk);
        As[akk][ar]     = v.x * arn;
        As[akk + 1][ar] = v.y * arn;
      }
      {
        const float* src = F + (size_t)(jb + br) * DIM + kb + bkk;
        float4 v0 = *(const float4*)(src);
        float4 v1 = *(const float4*)(src + 4);
        Bs[bkk + 0][br] = v0.x * brn;
        Bs[bkk + 1][br] = v0.y * brn;
        Bs[bkk + 2][br] = v0.z * brn;
        Bs[bkk + 3][br] = v0.w * brn;
        Bs[bkk + 4][br] = v1.x * brn;
        Bs[bkk + 5][br] = v1.y * brn;
        Bs[bkk + 6][br] = v1.z * brn;
        Bs[bkk + 7][br] = v1.w * brn;
      }
      __syncthreads();
#pragma unroll
      for (int k = 0; k < 32; ++k) {
        float4 a = *(const float4*)&As[k][4 * ry];
        float2 b = *(const float2*)&Bs[k][2 * tx];
        acc[0][0] += a.x * b.x; acc[0][1] += a.x * b.y;
        acc[1][0] += a.y * b.x; acc[1][1] += a.y * b.y;
        acc[2][0] += a.z * b.x; acc[2][1] += a.z * b.y;
        acc[3][0] += a.w * b.x; acc[3][1] += a.w * b.y;
      }
    }
#pragma unroll
    for (int r = 0; r < 4; ++r) {
      *(float2*)&simb[4 * ry + r][2 * tx] = make_float2(acc[r][0], acc[r][1]);
    }
    for (int rr = 0; rr < 4; ++rr) {
      const int r  = 4 * ry + rr;
      const int ig = ib + r;
      float v0 = simb[r][tx];
      float v1 = simb[r][64 + tx];
      if (jb + tx == ig)      v0 = -3.0e38f;
      if (jb + 64 + tx == ig) v1 = -3.0e38f;
      float cmin = topv[r][MCAND - 1];
      unsigned long long m0 = __ballot(v0 > cmin);
      unsigned long long m1 = __ballot(v1 > cmin);
      while (m0 | m1) {
        float v; int j;
        if (m0) {
          int l = __ffsll(m0) - 1; m0 &= (m0 - 1);
          v = __shfl(v0, l); j = jb + l;
        } else {
          int l = __ffsll(m1) - 1; m1 &= (m1 - 1);
          v = __shfl(v1, l); j = jb + 64 + l;
        }
        if (v > topv[r][MCAND - 1]) {
          int pos = MCAND - 1;
          while (pos > 0 && topv[r][pos - 1] < v) {
            topv[r][pos] = topv[r][pos - 1];
            topi[r][pos] = topi[r][pos - 1];
            --pos;
          }
          topv[r][pos] = v;
          topi[r][pos] = j;
        }
      }
    }
  }
  for (int rr = 0; rr < 4; ++rr) {
    const int r  = 4 * ry + rr;
    const int ig = ib + r;
    if (tx < MCAND) cand[(size_t)ig * MCAND + tx] = topi[r][tx];
  }
}

// ---------------------------------------------------------------------------
// Re-rank by fl32(truth): fn = fl32(F/n32) (materialized-f32 fn like ref),
// dot accumulated in f64 (f32xf32 exact), rounded to f32 at the end.
// Ties in f32 broken HIGH-index-first (reversed-argsort shim semantics).
// One block = 8 rows x 32 candidate-threads; each thread = one full dot.
// ---------------------------------------------------------------------------
__global__ __launch_bounds__(256) void refine_kernel(const float* __restrict__ F,
    const float* __restrict__ nrm, const int* __restrict__ cand,
    float* __restrict__ dens, float* __restrict__ knnf) {
#pragma clang fp contract(off)
  const int t  = threadIdx.x;
  const int i0 = blockIdx.x * 8;
  __shared__ __align__(16) float fni[8][DIM];   // 24 KB
  __shared__ float svals[8][MCAND];
  __shared__ int   sidx[8][MCAND];
  __shared__ float ssorted[8][MCAND];

  // stage fn_i rows: bit-exact f32 division by the truth-rounded f32 norm
  for (int r = 0; r < 8; ++r) {
    const float ni = nrm[i0 + r];
    const float* src = F + (size_t)(i0 + r) * DIM;
    for (int d = t; d < DIM; d += 256) fni[r][d] = src[d] / ni;
  }
  __syncthreads();

  const int row = t >> 5;       // 0..7
  const int c   = t & 31;       // candidate slot
  const int ig  = i0 + row;
  const int j   = cand[(size_t)ig * MCAND + c];
  const float nj = nrm[j];
  const float* fj = F + (size_t)j * DIM;
  const float* a  = fni[row];

  double acc = 0.0;
#pragma unroll 4
  for (int kq = 0; kq < 192; ++kq) {
    float4 bv = *(const float4*)(fj + 4 * kq);
    float4 av = *(const float4*)(a + 4 * kq);
    float b0 = bv.x / nj, b1 = bv.y / nj, b2 = bv.z / nj, b3 = bv.w / nj;
    acc += (double)av.x * (double)b0;
    acc += (double)av.y * (double)b1;
    acc += (double)av.z * (double)b2;
    acc += (double)av.w * (double)b3;
  }
  const float s = (float)acc;   // fl32(truth)

  svals[row][c] = s;
  sidx[row][c]  = j;
  __syncthreads();

  // rank among the 32 candidates: descending by f32 value,
  // exact f32 ties broken HIGHER index first
  int rank = 0;
  for (int k = 0; k < MCAND; ++k) {
    float vk = svals[row][k]; int jk = sidx[row][k];
    rank += (vk > s || (vk == s && jk > j)) ? 1 : 0;
  }
  if (rank < KNN) knnf[(size_t)ig * KNN + rank] = (float)j;
  ssorted[row][rank] = s;
  __syncthreads();

  // numpy pairwise mean over the 20 sorted-desc f32 values
  if (c == 0) {
    float rr[8];
#pragma unroll
    for (int q = 0; q < 8; ++q) rr[q] = ssorted[row][q];
#pragma unroll
    for (int q = 0; q < 8; ++q) rr[q] = rr[q] + ssorted[row][8 + q];
    float res = ((rr[0] + rr[1]) + (rr[2] + rr[3])) + ((rr[4] + rr[5]) + (rr[6] + rr[7]));
    res = res + ssorted[row][16];
    res = res + ssorted[row][17];
    res = res + ssorted[row][18];
    res = res + ssorted[row][19];
    dens[ig] = res / 20.0f;
  }
}

// ---------------------------------------------------------------------------
// peak_mask[i] = all(dens[i] > dens[knn[i][k]])  (f32 comparisons)
// ---------------------------------------------------------------------------
__global__ __launch_bounds__(256) void peak_kernel(const float* __restrict__ dens,
    const float* __restrict__ knnf, float* __restrict__ mask) {
  int i = blockIdx.x * 256 + threadIdx.x;
  if (i >= N_FEAT) return;
  float di = dens[i];
  int ok = 1;
#pragma unroll
  for (int k = 0; k < KNN; ++k) {
    int j = (int)knnf[(size_t)i * KNN + k];
    ok &= (di > dens[j]) ? 1 : 0;
  }
  mask[i] = ok ? 1.0f : 0.0f;
}

// ---------------------------------------------------------------------------
// preds = softmax(hn @ pn^T / tau) @ one_hot(labels)   (unchanged, passing)
// ---------------------------------------------------------------------------
__global__ __launch_bounds__(256) void preds_kernel(const float* __restrict__ H,
    const float* __restrict__ Pk, const int* __restrict__ labels,
    const float* __restrict__ rnh, const float* __restrict__ rnp,
    float* __restrict__ outp) {
  __shared__ __align__(16) float Hs[32][20];
  __shared__ __align__(16) float Ps[32][130];
  __shared__ float accc[16][C_CLS];

  const int t  = threadIdx.x;
  const int hb = blockIdx.x * 16;
  const int tx = t & 63;
  const int ry = t >> 6;
  const int hr  = t >> 4;
  const int hkk = (t & 15) * 2;
  const int pr  = t >> 1;
  const int pkk = (t & 1) * 16;
  const float hrn = rnh[hb + hr];

  for (int i = t; i < 16 * C_CLS; i += 256) ((float*)accc)[i] = 0.f;

  float m[4]    = {-3e38f, -3e38f, -3e38f, -3e38f};
  float ssum[4] = {0.f, 0.f, 0.f, 0.f};
  __syncthreads();

  for (int pt = 0; pt < 16; ++pt) {
    const int pb = pt * 128;
    const float prn = rnp[pb + pr];
    float acc[4][2];
#pragma unroll
    for (int r = 0; r < 4; ++r) { acc[r][0] = 0.f; acc[r][1] = 0.f; }

    for (int kc = 0; kc < 24; ++kc) {
      const int kb = kc * 32;
      __syncthreads();
      {
        float2 v = *(const float2*)(H + (size_t)(hb + hr) * DIM + kb + hkk);
        Hs[hkk][hr]     = v.x * hrn;
        Hs[hkk + 1][hr] = v.y * hrn;
      }
      {
        const float* src = Pk + (size_t)(pb + pr) * DIM + kb + pkk;
        float4 v0 = *(const float4*)(src);
        float4 v1 = *(const float4*)(src + 4);
        float4 v2 = *(const float4*)(src + 8);
        float4 v3 = *(const float4*)(src + 12);
        Ps[pkk +  0][pr] = v0.x * prn;  Ps[pkk +  1][pr] = v0.y * prn;
        Ps[pkk +  2][pr] = v0.z * prn;  Ps[pkk +  3][pr] = v0.w * prn;
        Ps[pkk +  4][pr] = v1.x * prn;  Ps[pkk +  5][pr] = v1.y * prn;
        Ps[pkk +  6][pr] = v1.z * prn;  Ps[pkk +  7][pr] = v1.w * prn;
        Ps[pkk +  8][pr] = v2.x * prn;  Ps[pkk +  9][pr] = v2.y * prn;
        Ps[pkk + 10][pr] = v2.z * prn;  Ps[pkk + 11][pr] = v2.w * prn;
        Ps[pkk + 12][pr] = v3.x * prn;  Ps[pkk + 13][pr] = v3.y * prn;
        Ps[pkk + 14][pr] = v3.z * prn;  Ps[pkk + 15][pr] = v3.w * prn;
      }
      __syncthreads();
#pragma unroll
      for (int k = 0; k < 32; ++k) {
        float4 a = *(const float4*)&Hs[k][4 * ry];
        float2 b = *(const float2*)&Ps[k][2 * tx];
        acc[0][0] += a.x * b.x; acc[0][1] += a.x * b.y;
        acc[1][0] += a.y * b.x; acc[1][1] += a.y * b.y;
        acc[2][0] += a.z * b.x; acc[2][1] += a.z * b.y;
        acc[3][0] += a.w * b.x; acc[3][1] += a.w * b.y;
      }
    }
    const int lab0 = labels[pb + 2 * tx];
    const int lab1 = labels[pb + 2 * tx + 1];
#pragma unroll
    for (int rr = 0; rr < 4; ++rr) {
      float l0 = acc[rr][0] / 0.07f;
      float l1 = acc[rr][1] / 0.07f;
      float tm = fmaxf(l0, l1);
#pragma unroll
      for (int off = 32; off; off >>= 1) tm = fmaxf(tm, __shfl_xor(tm, off));
      float mn = fmaxf(m[rr], tm);
      float sc = expf(m[rr] - mn);
      const int row = 4 * ry + rr;
#pragma unroll
      for (int q = 0; q < 4; ++q) accc[row][tx + 64 * q] *= sc;
      float e0 = expf(l0 - mn);
      float e1 = expf(l1 - mn);
      float es = e0 + e1;
#pragma unroll
      for (int off = 32; off; off >>= 1) es += __shfl_xor(es, off);
      ssum[rr] = ssum[rr] * sc + es;
      m[rr] = mn;
      atomicAdd(&accc[row][lab0], e0);
      atomicAdd(&accc[row][lab1], e1);
    }
  }
#pragma unroll
  for (int rr = 0; rr < 4; ++rr) {
    const int row = 4 * ry + rr;
    float inv = 1.0f / ssum[rr];
#pragma unroll
    for (int q = 0; q < 4; ++q) {
      outp[(size_t)(hb + row) * C_CLS + tx + 64 * q] = accc[row][tx + 64 * q] * inv;
    }
  }
}

// ---------------------------------------------------------------------------
extern "C" void kernel_launch(void* const* d_in, const int* in_sizes, int n_in,
                              void* d_out, int out_size, void* d_ws, size_t ws_size,
                              hipStream_t stream) {
  (void)in_sizes; (void)n_in; (void)out_size; (void)ws_size;
  const float* F      = (const float*)d_in[0];
  const float* H      = (const float*)d_in[1];
  const float* Pk     = (const float*)d_in[2];
  const int*   labels = (const int*)d_in[3];
  float* out = (float*)d_out;

  float* ws   = (float*)d_ws;
  float* nrmF = ws;                    // 8192 (truth-rounded f32 norms)
  float* rnF  = nrmF + N_FEAT;         // 8192 (fast reciprocals)
  float* nrmH = rnF + N_FEAT;          // 4096
  float* rnH  = nrmH + B_H;            // 4096
  float* nrmP = rnH + B_H;             // 2048
  float* rnP  = nrmP + P_PK;           // 2048
  int*   cand = (int*)(rnP + P_PK);    // 8192*32 int

  norm64_kernel<<<N_FEAT / 4, 256, 0, stream>>>(F, nrmF, rnF, N_FEAT);
  norm64_kernel<<<B_H / 4,  256, 0, stream>>>(H, nrmH, rnH, B_H);
  norm64_kernel<<<P_PK / 4, 256, 0, stream>>>(Pk, nrmP, rnP, P_PK);

  sim_topk_kernel<<<N_FEAT / 32, 512, 0, stream>>>(F, rnF, cand);

  refine_kernel<<<N_FEAT / 8, 256, 0, stream>>>(F, nrmF, cand,
      out + OUT_DENS_OFF, out + OUT_KNN_OFF);

  peak_kernel<<<N_FEAT / 256, 256, 0, stream>>>(out + OUT_DENS_OFF,
      out + OUT_KNN_OFF, out + OUT_MASK_OFF);

  preds_kernel<<<B_H / 16, 256, 0, stream>>>(H, Pk, labels, rnH, rnP, out);
}

// Round 9
// 1772.891 us; speedup vs baseline: 2.4514x; 2.4363x over previous
//
#include <hip/hip_runtime.h>
#include <math.h>

#define N_FEAT 8192
#define DIM    768
#define B_H    4096
#define P_PK   2048
#define C_CLS  256
#define KNN    20
#define MC     32     // candidates per col-half (union = 64 per row)

// output layout (all float32, concatenated in reference return order)
#define OUT_DENS_OFF  (B_H * C_CLS)                 // 1048576
#define OUT_KNN_OFF   (OUT_DENS_OFF + N_FEAT)       // 1056768
#define OUT_MASK_OFF  (OUT_KNN_OFF + N_FEAT * KNN)  // 1220608

typedef __attribute__((ext_vector_type(8))) short short8b;  // 8 bf16 (4 VGPR)
typedef __attribute__((ext_vector_type(4))) float f32x4;

// ---------------------------------------------------------------------------
// Truth-rounded f32 row norm: n32 = fl32( sqrt_f64( sum_f64(x^2) ) ).
// One wave per row. Also emits 1/n32 (fast path). [r8-verified]
// ---------------------------------------------------------------------------
__global__ __launch_bounds__(256) void norm64_kernel(const float* __restrict__ X,
    float* __restrict__ nrm, float* __restrict__ rn, int rows) {
  int w    = (int)((blockIdx.x * blockDim.x + threadIdx.x) >> 6);
  int lane = threadIdx.x & 63;
  if (w >= rows) return;
  const float* x = X + (size_t)w * DIM;
  double s = 0.0;
#pragma unroll
  for (int k = 0; k < 12; ++k) {
    float v = x[lane + 64 * k];
    s += (double)v * (double)v;
  }
#pragma unroll
  for (int off = 32; off; off >>= 1) s += __shfl_xor(s, off);
  if (lane == 0) {
    float n32 = (float)sqrt(s);
    nrm[w] = n32;
    rn[w]  = 1.0f / n32;
  }
}

// ---------------------------------------------------------------------------
// fn -> bf16 (RNE), row-scaled by 1/n32. Candidates only need ~1e-3.
// ---------------------------------------------------------------------------
__device__ inline unsigned short f2bf(float x) {
  unsigned u = __float_as_uint(x);
  return (unsigned short)((u + 0x7fffu + ((u >> 16) & 1u)) >> 16);
}

__global__ __launch_bounds__(256) void tobf16_kernel(const float* __restrict__ F,
    const float* __restrict__ rn, unsigned short* __restrict__ fnb) {
  int gid = (blockIdx.x * 256 + threadIdx.x) * 8;   // 768 % 8 == 0: one row
  int row = gid / DIM;
  float s = rn[row];
  float4 v0 = *(const float4*)(F + gid);
  float4 v1 = *(const float4*)(F + gid + 4);
  uint4 o;
  o.x = (unsigned)f2bf(v0.x * s) | ((unsigned)f2bf(v0.y * s) << 16);
  o.y = (unsigned)f2bf(v0.z * s) | ((unsigned)f2bf(v0.w * s) << 16);
  o.z = (unsigned)f2bf(v1.x * s) | ((unsigned)f2bf(v1.y * s) << 16);
  o.w = (unsigned)f2bf(v1.z * s) | ((unsigned)f2bf(v1.w * s) << 16);
  *(uint4*)(fnb + gid) = o;
}

// ---------------------------------------------------------------------------
// bf16-MFMA candidate GEMM + register-list top-32 selection.
// Grid 256 = 128 row-groups (64 rows) x 2 col-halves (4096 cols).
// 512 thr = 8 waves: wave w -> row-tile wr=w>>1 (16 rows), col-group wc=w&1.
// A frags (24 x short8b = 96 VGPR) live in registers for the whole sweep.
// B tile staged per (ct,kq): 128 cols x 128 k, granule-XOR-swizzled LDS
// (uniform banks for both the staging writes and the b-frag ds_read_b128).
// Selection: per ct, sim tile spilled to LDS; each wave owns 8 rows as 4
// half-pairs; top-32 list = one (val,idx) per lane of a 32-lane half;
// insert = argmin-replace + shfl_xor re-reduce (register-only, no LDS chain).
// ---------------------------------------------------------------------------
__global__ __launch_bounds__(512, 2) void sim_topk_mfma(
    const unsigned short* __restrict__ fnb, int* __restrict__ cand) {
  __shared__ __align__(16) uint4 Bs[128 * 17];      // 34816 B (17th granule = pad)
  __shared__ __align__(16) float simb[64][130];     // 33280 B

  const int t  = threadIdx.x;
  const int l  = t & 63;
  const int w  = t >> 6;            // wave 0..7
  const int wr = w >> 1;            // row-tile 0..3
  const int wc = w & 1;             // col-group 0..1
  const int rg = blockIdx.x >> 1;
  const int hg = blockIdx.x & 1;    // column half
  const int ib = rg * 64;
  const int jb0 = hg * 4096;

  const int lr = l & 15;            // fragment row/col index
  const int lk = l >> 4;            // fragment k-slot 0..3
  const int sx = lk ^ (lr & 3);     // b-frag swizzle slot (c&3 == lr&3)

  // staging map: thread -> (col 0..127, quad 0..3), swizzle by col&3
  const int scol = t >> 2;
  const int sq   = t & 3;
  const int ssw  = scol & 3;

  // ---- A fragments in registers (rows ib+wr*16+lr, all K)
  short8b a[24];
  {
    const unsigned short* ap = fnb + (size_t)(ib + wr * 16 + lr) * DIM + lk * 8;
#pragma unroll
    for (int kc = 0; kc < 24; ++kc) a[kc] = *(const short8b*)(ap + kc * 32);
  }

  // ---- selection state: 4 row-pairs per wave; lane q of half h = 1 entry
  const int h = l >> 5;
  const int q = l & 31;
  float lv[4], cmv[4];
  int   li[4], cml[4];
#pragma unroll
  for (int p = 0; p < 4; ++p) { lv[p] = -3e38f; li[p] = 0; cmv[p] = -3e38f; cml[p] = 0; }

  const int c0 = wc * 64 + lr;      // b-frag col for ctl=0 (+16 per ctl)

#pragma unroll 1
  for (int ct = 0; ct < 32; ++ct) {
    const int jbct = jb0 + ct * 128;
    f32x4 acc0 = {0.f, 0.f, 0.f, 0.f};
    f32x4 acc1 = {0.f, 0.f, 0.f, 0.f};
    f32x4 acc2 = {0.f, 0.f, 0.f, 0.f};
    f32x4 acc3 = {0.f, 0.f, 0.f, 0.f};
    const unsigned short* colbase = fnb + (size_t)(jbct + scol) * DIM;

#pragma unroll
    for (int kq = 0; kq < 6; ++kq) {
      __syncthreads();   // Bs consumed by previous kq's MFMAs
      { // stage: read granules in swizzle-permuted order, write LDS linearly
        const unsigned short* gb = colbase + kq * 128 + sq * 32;
        uint4 v0 = *(const uint4*)(gb + ((0 ^ ssw) * 8));
        uint4 v1 = *(const uint4*)(gb + ((1 ^ ssw) * 8));
        uint4 v2 = *(const uint4*)(gb + ((2 ^ ssw) * 8));
        uint4 v3 = *(const uint4*)(gb + ((3 ^ ssw) * 8));
        uint4* bd = &Bs[scol * 17 + sq * 4];
        bd[0] = v0; bd[1] = v1; bd[2] = v2; bd[3] = v3;
      }
      __syncthreads();
#pragma unroll
      for (int ks = 0; ks < 4; ++ks) {
        const short8b av = a[kq * 4 + ks];
        const short8b b0 = *(const short8b*)&Bs[(c0 +  0) * 17 + ks * 4 + sx];
        const short8b b1 = *(const short8b*)&Bs[(c0 + 16) * 17 + ks * 4 + sx];
        const short8b b2 = *(const short8b*)&Bs[(c0 + 32) * 17 + ks * 4 + sx];
        const short8b b3 = *(const short8b*)&Bs[(c0 + 48) * 17 + ks * 4 + sx];
        acc0 = __builtin_amdgcn_mfma_f32_16x16x32_bf16(av, b0, acc0, 0, 0, 0);
        acc1 = __builtin_amdgcn_mfma_f32_16x16x32_bf16(av, b1, acc1, 0, 0, 0);
        acc2 = __builtin_amdgcn_mfma_f32_16x16x32_bf16(av, b2, acc2, 0, 0, 0);
        acc3 = __builtin_amdgcn_mfma_f32_16x16x32_bf16(av, b3, acc3, 0, 0, 0);
      }
    }

    // ---- spill sim tile (C/D layout: col=lane&15, row=4*(lane>>4)+reg)
    {
      const int r0 = wr * 16 + lk * 4;
      const int cb = wc * 64 + lr;
#pragma unroll
      for (int reg = 0; reg < 4; ++reg) {
        simb[r0 + reg][cb +  0] = acc0[reg];
        simb[r0 + reg][cb + 16] = acc1[reg];
        simb[r0 + reg][cb + 32] = acc2[reg];
        simb[r0 + reg][cb + 48] = acc3[reg];
      }
    }
    __syncthreads();

    // ---- selection: wave w owns rows w*8..w*8+7 as 4 (h=0,h=1) pairs
#pragma unroll
    for (int p = 0; p < 4; ++p) {
      const int r  = w * 8 + 2 * p + h;
      const int ig = ib + r;
#pragma unroll
      for (int s = 0; s < 4; ++s) {
        float v  = simb[r][32 * s + q];
        int   jj = jbct + 32 * s + q;
        bool pred = (v > cmv[p]) && (jj != ig);
        unsigned long long bm = __ballot(pred);
        unsigned hm = (unsigned)(bm >> (h * 32));
        while (hm) {
          int lb = __ffs(hm) - 1;
          hm &= hm - 1;
          float bv = __shfl(v,  h * 32 + lb);
          int   bj = __shfl(jj, h * 32 + lb);
          if (bv > cmv[p]) {
            if (q == cml[p]) { lv[p] = bv; li[p] = bj; }
            float ov = lv[p]; int ol = q;
#pragma unroll
            for (int d = 1; d <= 16; d <<= 1) {
              float tv = __shfl_xor(ov, d);
              int   tl = __shfl_xor(ol, d);
              if (tv < ov || (tv == ov && tl < ol)) { ov = tv; ol = tl; }
            }
            cmv[p] = ov; cml[p] = ol;
          }
        }
      }
    }
  }

  // ---- emit candidates (unsorted; exact refine ranks them)
#pragma unroll
  for (int p = 0; p < 4; ++p) {
    const int ig = ib + w * 8 + 2 * p + h;
    cand[(size_t)ig * (2 * MC) + hg * MC + q] = li[p];
  }
}

// ---------------------------------------------------------------------------
// Exact re-rank of 64 candidates per row, identical comparator to r8:
// fn = fl32(F/n32); dot in f64 (f32xf32 exact); rank by f32 value desc,
// exact-f32 ties -> HIGHER index first; numpy pairwise n=20 mean.
// One block per row, 4 waves x 16 candidate dots.
// ---------------------------------------------------------------------------
__global__ __launch_bounds__(256) void refine64_kernel(const float* __restrict__ F,
    const float* __restrict__ nrm, const int* __restrict__ cand,
    float* __restrict__ dens, float* __restrict__ knnf) {
#pragma clang fp contract(off)
  const int i = blockIdx.x;
  const int t = threadIdx.x;
  const int l = t & 63;
  const int w = t >> 6;
  __shared__ __align__(16) float fni[DIM];
  __shared__ float s32v[64];
  __shared__ int   vidx[64];
  __shared__ float ssorted[KNN];

  const float ni = nrm[i];
  for (int d = t; d < DIM; d += 256) fni[d] = F[(size_t)i * DIM + d] / ni;
  if (t < 64) vidx[t] = cand[(size_t)i * 64 + t];
  __syncthreads();

  for (int c = w * 16; c < w * 16 + 16; ++c) {
    const int j = vidx[c];
    const float* fj = F + (size_t)j * DIM;
    const float nj = nrm[j];
    double s = 0.0;
#pragma unroll
    for (int k2 = 0; k2 < 12; ++k2) {
      float fjn = fj[l + 64 * k2] / nj;                 // exact f32 fn bits
      s += (double)fni[l + 64 * k2] * (double)fjn;      // exact product in f64
    }
#pragma unroll
    for (int off = 32; off; off >>= 1) s += __shfl_xor(s, off);
    if (l == 0) s32v[c] = (float)s;                     // fl32(truth)
  }
  __syncthreads();

  if (t < 64) {
    const float v = s32v[t];
    const int   j = vidx[t];
    int rank = 0;
    for (int k = 0; k < 64; ++k) {
      float vk = s32v[k]; int jk = vidx[k];
      rank += (vk > v || (vk == v && jk > j)) ? 1 : 0;
    }
    if (rank < KNN) {
      knnf[(size_t)i * KNN + rank] = (float)j;
      ssorted[rank] = v;
    }
  }
  __syncthreads();

  if (t == 0) {
    float rr[8];
#pragma unroll
    for (int u = 0; u < 8; ++u) rr[u] = ssorted[u];
#pragma unroll
    for (int u = 0; u < 8; ++u) rr[u] = rr[u] + ssorted[8 + u];
    float res = ((rr[0] + rr[1]) + (rr[2] + rr[3])) + ((rr[4] + rr[5]) + (rr[6] + rr[7]));
    res = res + ssorted[16];
    res = res + ssorted[17];
    res = res + ssorted[18];
    res = res + ssorted[19];
    dens[i] = res / 20.0f;
  }
}

// ---------------------------------------------------------------------------
// peak_mask[i] = all(dens[i] > dens[knn[i][k]])  (f32 comparisons) [r8]
// ---------------------------------------------------------------------------
__global__ __launch_bounds__(256) void peak_kernel(const float* __restrict__ dens,
    const float* __restrict__ knnf, float* __restrict__ mask) {
  int i = blockIdx.x * 256 + threadIdx.x;
  if (i >= N_FEAT) return;
  float di = dens[i];
  int ok = 1;
#pragma unroll
  for (int k = 0; k < KNN; ++k) {
    int j = (int)knnf[(size_t)i * KNN + k];
    ok &= (di > dens[j]) ? 1 : 0;
  }
  mask[i] = ok ? 1.0f : 0.0f;
}

// ---------------------------------------------------------------------------
// preds = softmax(hn @ pn^T / tau) @ one_hot(labels)  [r8-verified, unchanged]
// ---------------------------------------------------------------------------
__global__ __launch_bounds__(256) void preds_kernel(const float* __restrict__ H,
    const float* __restrict__ Pk, const int* __restrict__ labels,
    const float* __restrict__ rnh, const float* __restrict__ rnp,
    float* __restrict__ outp) {
  __shared__ __align__(16) float Hs[32][20];
  __shared__ __align__(16) float Ps[32][130];
  __shared__ float accc[16][C_CLS];

  const int t  = threadIdx.x;
  const int hb = blockIdx.x * 16;
  const int tx = t & 63;
  const int ry = t >> 6;
  const int hr  = t >> 4;
  const int hkk = (t & 15) * 2;
  const int pr  = t >> 1;
  const int pkk = (t & 1) * 16;
  const float hrn = rnh[hb + hr];

  for (int i = t; i < 16 * C_CLS; i += 256) ((float*)accc)[i] = 0.f;

  float m[4]    = {-3e38f, -3e38f, -3e38f, -3e38f};
  float ssum[4] = {0.f, 0.f, 0.f, 0.f};
  __syncthreads();

  for (int pt = 0; pt < 16; ++pt) {
    const int pb = pt * 128;
    const float prn = rnp[pb + pr];
    float acc[4][2];
#pragma unroll
    for (int r = 0; r < 4; ++r) { acc[r][0] = 0.f; acc[r][1] = 0.f; }

    for (int kc = 0; kc < 24; ++kc) {
      const int kb = kc * 32;
      __syncthreads();
      {
        float2 v = *(const float2*)(H + (size_t)(hb + hr) * DIM + kb + hkk);
        Hs[hkk][hr]     = v.x * hrn;
        Hs[hkk + 1][hr] = v.y * hrn;
      }
      {
        const float* src = Pk + (size_t)(pb + pr) * DIM + kb + pkk;
        float4 v0 = *(const float4*)(src);
        float4 v1 = *(const float4*)(src + 4);
        float4 v2 = *(const float4*)(src + 8);
        float4 v3 = *(const float4*)(src + 12);
        Ps[pkk +  0][pr] = v0.x * prn;  Ps[pkk +  1][pr] = v0.y * prn;
        Ps[pkk +  2][pr] = v0.z * prn;  Ps[pkk +  3][pr] = v0.w * prn;
        Ps[pkk +  4][pr] = v1.x * prn;  Ps[pkk +  5][pr] = v1.y * prn;
        Ps[pkk +  6][pr] = v1.z * prn;  Ps[pkk +  7][pr] = v1.w * prn;
        Ps[pkk +  8][pr] = v2.x * prn;  Ps[pkk +  9][pr] = v2.y * prn;
        Ps[pkk + 10][pr] = v2.z * prn;  Ps[pkk + 11][pr] = v2.w * prn;
        Ps[pkk + 12][pr] = v3.x * prn;  Ps[pkk + 13][pr] = v3.y * prn;
        Ps[pkk + 14][pr] = v3.z * prn;  Ps[pkk + 15][pr] = v3.w * prn;
      }
      __syncthreads();
#pragma unroll
      for (int k = 0; k < 32; ++k) {
        float4 a = *(const float4*)&Hs[k][4 * ry];
        float2 b = *(const float2*)&Ps[k][2 * tx];
        acc[0][0] += a.x * b.x; acc[0][1] += a.x * b.y;
        acc[1][0] += a.y * b.x; acc[1][1] += a.y * b.y;
        acc[2][0] += a.z * b.x; acc[2][1] += a.z * b.y;
        acc[3][0] += a.w * b.x; acc[3][1] += a.w * b.y;
      }
    }
    const int lab0 = labels[pb + 2 * tx];
    const int lab1 = labels[pb + 2 * tx + 1];
#pragma unroll
    for (int rr = 0; rr < 4; ++rr) {
      float l0 = acc[rr][0] / 0.07f;
      float l1 = acc[rr][1] / 0.07f;
      float tm = fmaxf(l0, l1);
#pragma unroll
      for (int off = 32; off; off >>= 1) tm = fmaxf(tm, __shfl_xor(tm, off));
      float mn = fmaxf(m[rr], tm);
      float sc = expf(m[rr] - mn);
      const int row = 4 * ry + rr;
#pragma unroll
      for (int qq = 0; qq < 4; ++qq) accc[row][tx + 64 * qq] *= sc;
      float e0 = expf(l0 - mn);
      float e1 = expf(l1 - mn);
      float es = e0 + e1;
#pragma unroll
      for (int off = 32; off; off >>= 1) es += __shfl_xor(es, off);
      ssum[rr] = ssum[rr] * sc + es;
      m[rr] = mn;
      atomicAdd(&accc[row][lab0], e0);
      atomicAdd(&accc[row][lab1], e1);
    }
  }
#pragma unroll
  for (int rr = 0; rr < 4; ++rr) {
    const int row = 4 * ry + rr;
    float inv = 1.0f / ssum[rr];
#pragma unroll
    for (int qq = 0; qq < 4; ++qq) {
      outp[(size_t)(hb + row) * C_CLS + tx + 64 * qq] = accc[row][tx + 64 * qq] * inv;
    }
  }
}

// ---------------------------------------------------------------------------
extern "C" void kernel_launch(void* const* d_in, const int* in_sizes, int n_in,
                              void* d_out, int out_size, void* d_ws, size_t ws_size,
                              hipStream_t stream) {
  (void)in_sizes; (void)n_in; (void)out_size; (void)ws_size;
  const float* F      = (const float*)d_in[0];
  const float* H      = (const float*)d_in[1];
  const float* Pk     = (const float*)d_in[2];
  const int*   labels = (const int*)d_in[3];
  float* out = (float*)d_out;

  // ws layout (~14.8 MB): norms | cand(64/row) | fnb bf16
  float* ws   = (float*)d_ws;
  float* nrmF = ws;                               // 8192
  float* rnF  = nrmF + N_FEAT;                    // 8192
  float* nrmH = rnF + N_FEAT;                     // 4096
  float* rnH  = nrmH + B_H;                       // 4096
  float* nrmP = rnH + B_H;                        // 2048
  float* rnP  = nrmP + P_PK;                      // 2048
  int*   cand = (int*)(rnP + P_PK);               // 8192*64 (16B-aligned)
  unsigned short* fnb = (unsigned short*)(cand + N_FEAT * 64);  // 8192*768

  norm64_kernel<<<N_FEAT / 4, 256, 0, stream>>>(F, nrmF, rnF, N_FEAT);
  norm64_kernel<<<B_H / 4,  256, 0, stream>>>(H, nrmH, rnH, B_H);
  norm64_kernel<<<P_PK / 4, 256, 0, stream>>>(Pk, nrmP, rnP, P_PK);

  tobf16_kernel<<<N_FEAT * DIM / (8 * 256), 256, 0, stream>>>(F, rnF, fnb);

  sim_topk_mfma<<<256, 512, 0, stream>>>(fnb, cand);

  refine64_kernel<<<N_FEAT, 256, 0, stream>>>(F, nrmF, cand,
      out + OUT_DENS_OFF, out + OUT_KNN_OFF);

  peak_kernel<<<N_FEAT / 256, 256, 0, stream>>>(out + OUT_DENS_OFF,
      out + OUT_KNN_OFF, out + OUT_MASK_OFF);

  preds_kernel<<<B_H / 16, 256, 0, stream>>>(H, Pk, labels, rnH, rnP, out);
}

// Round 10
// 1373.843 us; speedup vs baseline: 3.1634x; 1.2905x over previous
//
#include <hip/hip_runtime.h>
#include <math.h>

#define N_FEAT 8192
#define DIM    768
#define B_H    4096
#define P_PK   2048
#define C_CLS  256
#define KNN    20

// output layout (all float32, concatenated in reference return order)
#define OUT_DENS_OFF  (B_H * C_CLS)                 // 1048576
#define OUT_KNN_OFF   (OUT_DENS_OFF + N_FEAT)       // 1056768
#define OUT_MASK_OFF  (OUT_KNN_OFF + N_FEAT * KNN)  // 1220608

typedef __attribute__((ext_vector_type(8)))  short short8b;  // 8 bf16
typedef __attribute__((ext_vector_type(16))) float f32x16;

// ---------------------------------------------------------------------------
// Truth-rounded f32 row norm: n32 = fl32( sqrt_f64( sum_f64(x^2) ) ). [r8]
// ---------------------------------------------------------------------------
__global__ __launch_bounds__(256) void norm64_kernel(const float* __restrict__ X,
    float* __restrict__ nrm, float* __restrict__ rn, int rows) {
  int w    = (int)((blockIdx.x * blockDim.x + threadIdx.x) >> 6);
  int lane = threadIdx.x & 63;
  if (w >= rows) return;
  const float* x = X + (size_t)w * DIM;
  double s = 0.0;
#pragma unroll
  for (int k = 0; k < 12; ++k) {
    float v = x[lane + 64 * k];
    s += (double)v * (double)v;
  }
#pragma unroll
  for (int off = 32; off; off >>= 1) s += __shfl_xor(s, off);
  if (lane == 0) {
    float n32 = (float)sqrt(s);
    nrm[w] = n32;
    rn[w]  = 1.0f / n32;
  }
}

// ---------------------------------------------------------------------------
// fn -> bf16 (RNE), row-scaled by 1/n32 (candidate path, ~1e-3 accuracy ok)
// ---------------------------------------------------------------------------
__device__ inline unsigned short f2bf(float x) {
  unsigned u = __float_as_uint(x);
  return (unsigned short)((u + 0x7fffu + ((u >> 16) & 1u)) >> 16);
}

__global__ __launch_bounds__(256) void tobf16_kernel(const float* __restrict__ F,
    const float* __restrict__ rn, unsigned short* __restrict__ fnb) {
  int gid = (blockIdx.x * 256 + threadIdx.x) * 8;
  int row = gid / DIM;
  float s = rn[row];
  float4 v0 = *(const float4*)(F + gid);
  float4 v1 = *(const float4*)(F + gid + 4);
  uint4 o;
  o.x = (unsigned)f2bf(v0.x * s) | ((unsigned)f2bf(v0.y * s) << 16);
  o.y = (unsigned)f2bf(v0.z * s) | ((unsigned)f2bf(v0.w * s) << 16);
  o.z = (unsigned)f2bf(v1.x * s) | ((unsigned)f2bf(v1.y * s) << 16);
  o.w = (unsigned)f2bf(v1.z * s) | ((unsigned)f2bf(v1.w * s) << 16);
  *(uint4*)(fnb + gid) = o;
}

// ---------------------------------------------------------------------------
// fn32 = F / n32 — exact IEEE f32 quotients, materialized ONCE (refine path)
// ---------------------------------------------------------------------------
__global__ __launch_bounds__(256) void tofn32_kernel(const float* __restrict__ F,
    const float* __restrict__ nrm, float* __restrict__ fn32) {
#pragma clang fp contract(off)
  int gid = (blockIdx.x * 256 + threadIdx.x) * 4;
  int row = gid / DIM;
  float ni = nrm[row];
  float4 v = *(const float4*)(F + gid);
  v.x = v.x / ni; v.y = v.y / ni; v.z = v.z / ni; v.w = v.w / ni;
  *(float4*)(fn32 + gid) = v;
}

// ---------------------------------------------------------------------------
// bf16 32x32x16-MFMA candidate GEMM + register-list top-32 selection.
// Grid 256 = 128 row-groups (64 rows) x 2 col-halves. 512 thr = 8 waves:
// wave w: row-tile wr=w>>2 (32 rows, A frags in 192 VGPR), col-tile wc=w&3.
// B tile: double-buffered LDS, col-stride 17 granules, slot = kk ^ 4(col&3)
// -> conflict-free ds_write_b128 AND ds_read_b128 (8 lanes per bank-quad).
// One barrier per kq; next kq's coalesced loads issued under MFMA phase.
// Selection: 32-entry (val,idx) per lane of a 32-lane half; insert =
// ballot-located argmin replace + value-only 5-shfl min rebuild.
// ---------------------------------------------------------------------------
__global__ __launch_bounds__(512, 2) void sim_topk_mfma(
    const unsigned short* __restrict__ fnb, int* __restrict__ cand) {
  __shared__ __align__(16) uint4 Bs[2][128 * 17];   // 2 x 34816 B
  __shared__ __align__(16) float simb[64][130];     // 33280 B

  const int t  = threadIdx.x;
  const int l  = t & 63;
  const int w  = t >> 6;
  const int wr = w >> 2;            // row-tile 0..1
  const int wc = w & 3;             // col-tile 0..3
  const int rg = blockIdx.x >> 1;
  const int hg = blockIdx.x & 1;
  const int ib = rg * 64;
  const int jb0 = hg * 4096;

  const int lc = l & 31;            // frag row/col
  const int lh = l >> 5;            // k-half
  const int bsw = 4 * (lc & 3);     // read-side slot swizzle

  // staging map: thread -> col 0..127, 64B quad sq
  const int scol = t >> 2;
  const int sq   = t & 3;
  const int wsw  = sq ^ (scol & 3); // write-side slot base

  // ---- A fragments in registers: rows ib + wr*32 + lc, 48 k-chunks of 16
  short8b a[48];
  {
    const unsigned short* ap = fnb + (size_t)(ib + wr * 32 + lc) * DIM + lh * 8;
#pragma unroll
    for (int kc = 0; kc < 48; ++kc) a[kc] = *(const short8b*)(ap + kc * 16);
  }

  // ---- selection state
  const int h = l >> 5;
  const int q = l & 31;
  float lv[4], cmv[4];
  int   li[4];
#pragma unroll
  for (int p = 0; p < 4; ++p) { lv[p] = -3e38f; li[p] = 0; cmv[p] = -3e38f; }

  // ---- prologue: load (ct=0, kq=0)
  uint4 v0, v1, v2, v3;
  {
    const unsigned short* gb = fnb + (size_t)(jb0 + scol) * DIM + sq * 32;
    v0 = *(const uint4*)(gb);
    v1 = *(const uint4*)(gb + 8);
    v2 = *(const uint4*)(gb + 16);
    v3 = *(const uint4*)(gb + 24);
  }
  int cur = 0;

#pragma unroll 1
  for (int ct = 0; ct < 32; ++ct) {
    f32x16 acc;
#pragma unroll
    for (int i = 0; i < 16; ++i) acc[i] = 0.f;

#pragma unroll
    for (int kq = 0; kq < 6; ++kq) {
      { // write staged regs (conflict-free: slots 4*(sq^a)+i)
        uint4* bd = &Bs[cur][scol * 17 + 4 * wsw];
        bd[0] = v0; bd[1] = v1; bd[2] = v2; bd[3] = v3;
      }
      __syncthreads();
      if (!(ct == 31 && kq == 5)) {   // issue next tile's loads under MFMA
        const int nct = (kq == 5) ? ct + 1 : ct;
        const int nkq = (kq == 5) ? 0 : kq + 1;
        const unsigned short* gb =
            fnb + (size_t)(jb0 + nct * 128 + scol) * DIM + nkq * 128 + sq * 32;
        v0 = *(const uint4*)(gb);
        v1 = *(const uint4*)(gb + 8);
        v2 = *(const uint4*)(gb + 16);
        v3 = *(const uint4*)(gb + 24);
      }
#pragma unroll
      for (int s = 0; s < 8; ++s) {
        const int slot = (2 * s + lh) ^ bsw;
        const short8b b = *(const short8b*)&Bs[cur][(wc * 32 + lc) * 17 + slot];
        acc = __builtin_amdgcn_mfma_f32_32x32x16_bf16(a[kq * 8 + s], b, acc, 0, 0, 0);
      }
      cur ^= 1;
    }

    // ---- spill sim tile (32x32 C/D: col=l&31, row=(reg&3)+8(reg>>2)+4(l>>5))
#pragma unroll
    for (int reg = 0; reg < 16; ++reg) {
      simb[wr * 32 + (reg & 3) + 8 * (reg >> 2) + 4 * lh][wc * 32 + lc] = acc[reg];
    }
    __syncthreads();

    // ---- selection: wave w owns rows 8w..8w+7 as 4 (h=0,h=1) pairs
    const int jbct = jb0 + ct * 128;
#pragma unroll
    for (int p = 0; p < 4; ++p) {
      const int r  = w * 8 + 2 * p + h;
      const int ig = ib + r;
#pragma unroll
      for (int s = 0; s < 4; ++s) {
        float v  = simb[r][32 * s + q];
        int   jj = jbct + 32 * s + q;
        bool pred = (v > cmv[p]) && (jj != ig);
        unsigned long long bm = __ballot(pred);
        unsigned hm = (unsigned)(bm >> (h * 32));
        while (hm) {
          const int lb = __ffs(hm) - 1;
          hm &= hm - 1;
          const float bv = __shfl(v,  h * 32 + lb);
          const int   bj = __shfl(jj, h * 32 + lb);
          if (bv > cmv[p]) {
            unsigned em = (unsigned)(__ballot(lv[p] == cmv[p]) >> (h * 32));
            if (q == __ffs(em) - 1) { lv[p] = bv; li[p] = bj; }
            float ov = lv[p];
#pragma unroll
            for (int d = 1; d <= 16; d <<= 1) ov = fminf(ov, __shfl_xor(ov, d));
            cmv[p] = ov;
          }
        }
      }
    }
    // no trailing barrier: next simb write is >=6 barriers away
  }

  // ---- emit candidates (unsorted; exact refine ranks them)
#pragma unroll
  for (int p = 0; p < 4; ++p) {
    const int ig = ib + w * 8 + 2 * p + h;
    cand[(size_t)ig * 64 + hg * 32 + q] = li[p];
  }
}

// ---------------------------------------------------------------------------
// Exact re-rank (fn32 path): identical comparator to r8/r9 — fl32(f64-exact
// dot of f32 fn bits), desc, exact-f32 ties -> HIGHER index; pairwise mean.
// ---------------------------------------------------------------------------
__global__ __launch_bounds__(256) void refine64_fn32(const float* __restrict__ fn32,
    const int* __restrict__ cand, float* __restrict__ dens, float* __restrict__ knnf) {
#pragma clang fp contract(off)
  const int i = blockIdx.x;
  const int t = threadIdx.x;
  const int l = t & 63;
  const int w = t >> 6;
  __shared__ __align__(16) float fni[DIM];
  __shared__ float s32v[64];
  __shared__ int   vidx[64];
  __shared__ float ssorted[KNN];

  const float* fni_g = fn32 + (size_t)i * DIM;
  for (int d = t; d < DIM; d += 256) fni[d] = fni_g[d];
  if (t < 64) vidx[t] = cand[(size_t)i * 64 + t];
  __syncthreads();

  for (int c = w * 16; c < w * 16 + 16; ++c) {
    const int j = vidx[c];
    const float* fj = fn32 + (size_t)j * DIM;
    double s = 0.0;
#pragma unroll
    for (int k2 = 0; k2 < 12; ++k2) {
      s += (double)fni[l + 64 * k2] * (double)fj[l + 64 * k2];
    }
#pragma unroll
    for (int off = 32; off; off >>= 1) s += __shfl_xor(s, off);
    if (l == 0) s32v[c] = (float)s;
  }
  __syncthreads();

  if (t < 64) {
    const float v = s32v[t];
    const int   j = vidx[t];
    int rank = 0;
    for (int k = 0; k < 64; ++k) {
      float vk = s32v[k]; int jk = vidx[k];
      rank += (vk > v || (vk == v && jk > j)) ? 1 : 0;
    }
    if (rank < KNN) {
      knnf[(size_t)i * KNN + rank] = (float)j;
      ssorted[rank] = v;
    }
  }
  __syncthreads();

  if (t == 0) {
    float rr[8];
#pragma unroll
    for (int u = 0; u < 8; ++u) rr[u] = ssorted[u];
#pragma unroll
    for (int u = 0; u < 8; ++u) rr[u] = rr[u] + ssorted[8 + u];
    float res = ((rr[0] + rr[1]) + (rr[2] + rr[3])) + ((rr[4] + rr[5]) + (rr[6] + rr[7]));
    res = res + ssorted[16];
    res = res + ssorted[17];
    res = res + ssorted[18];
    res = res + ssorted[19];
    dens[i] = res / 20.0f;
  }
}

// ---------------------------------------------------------------------------
// Fallback refine (r9 verbatim, divisions in-kernel) if ws is too small
// ---------------------------------------------------------------------------
__global__ __launch_bounds__(256) void refine64_div(const float* __restrict__ F,
    const float* __restrict__ nrm, const int* __restrict__ cand,
    float* __restrict__ dens, float* __restrict__ knnf) {
#pragma clang fp contract(off)
  const int i = blockIdx.x;
  const int t = threadIdx.x;
  const int l = t & 63;
  const int w = t >> 6;
  __shared__ __align__(16) float fni[DIM];
  __shared__ float s32v[64];
  __shared__ int   vidx[64];
  __shared__ float ssorted[KNN];

  const float ni = nrm[i];
  for (int d = t; d < DIM; d += 256) fni[d] = F[(size_t)i * DIM + d] / ni;
  if (t < 64) vidx[t] = cand[(size_t)i * 64 + t];
  __syncthreads();

  for (int c = w * 16; c < w * 16 + 16; ++c) {
    const int j = vidx[c];
    const float* fj = F + (size_t)j * DIM;
    const float nj = nrm[j];
    double s = 0.0;
#pragma unroll
    for (int k2 = 0; k2 < 12; ++k2) {
      float fjn = fj[l + 64 * k2] / nj;
      s += (double)fni[l + 64 * k2] * (double)fjn;
    }
#pragma unroll
    for (int off = 32; off; off >>= 1) s += __shfl_xor(s, off);
    if (l == 0) s32v[c] = (float)s;
  }
  __syncthreads();

  if (t < 64) {
    const float v = s32v[t];
    const int   j = vidx[t];
    int rank = 0;
    for (int k = 0; k < 64; ++k) {
      float vk = s32v[k]; int jk = vidx[k];
      rank += (vk > v || (vk == v && jk > j)) ? 1 : 0;
    }
    if (rank < KNN) {
      knnf[(size_t)i * KNN + rank] = (float)j;
      ssorted[rank] = v;
    }
  }
  __syncthreads();

  if (t == 0) {
    float rr[8];
#pragma unroll
    for (int u = 0; u < 8; ++u) rr[u] = ssorted[u];
#pragma unroll
    for (int u = 0; u < 8; ++u) rr[u] = rr[u] + ssorted[8 + u];
    float res = ((rr[0] + rr[1]) + (rr[2] + rr[3])) + ((rr[4] + rr[5]) + (rr[6] + rr[7]));
    res = res + ssorted[16];
    res = res + ssorted[17];
    res = res + ssorted[18];
    res = res + ssorted[19];
    dens[i] = res / 20.0f;
  }
}

// ---------------------------------------------------------------------------
// peak_mask[i] = all(dens[i] > dens[knn[i][k]])  [r8]
// ---------------------------------------------------------------------------
__global__ __launch_bounds__(256) void peak_kernel(const float* __restrict__ dens,
    const float* __restrict__ knnf, float* __restrict__ mask) {
  int i = blockIdx.x * 256 + threadIdx.x;
  if (i >= N_FEAT) return;
  float di = dens[i];
  int ok = 1;
#pragma unroll
  for (int k = 0; k < KNN; ++k) {
    int j = (int)knnf[(size_t)i * KNN + k];
    ok &= (di > dens[j]) ? 1 : 0;
  }
  mask[i] = ok ? 1.0f : 0.0f;
}

// ---------------------------------------------------------------------------
// preds = softmax(hn @ pn^T / tau) @ one_hot(labels)
// 8 h-rows per block (grid 512 -> 2 blocks/CU for latency hiding).
// ---------------------------------------------------------------------------
__global__ __launch_bounds__(256) void preds_kernel(const float* __restrict__ H,
    const float* __restrict__ Pk, const int* __restrict__ labels,
    const float* __restrict__ rnh, const float* __restrict__ rnp,
    float* __restrict__ outp) {
  __shared__ __align__(16) float Hs[32][12];
  __shared__ __align__(16) float Ps[32][130];
  __shared__ float accc[8][C_CLS];

  const int t  = threadIdx.x;
  const int hb = blockIdx.x * 8;
  const int tx = t & 63;
  const int ry = t >> 6;           // wave 0..3 -> rows 2ry, 2ry+1
  const int hr  = t >> 5;          // 0..7
  const int hkk = t & 31;          // 0..31
  const int pr  = t >> 1;
  const int pkk = (t & 1) * 16;
  const float hrn = rnh[hb + hr];

  for (int i = t; i < 8 * C_CLS; i += 256) ((float*)accc)[i] = 0.f;

  float m[2]    = {-3e38f, -3e38f};
  float ssum[2] = {0.f, 0.f};
  __syncthreads();

  for (int pt = 0; pt < 16; ++pt) {
    const int pb = pt * 128;
    const float prn = rnp[pb + pr];
    float acc[2][2] = {{0.f, 0.f}, {0.f, 0.f}};

    for (int kc = 0; kc < 24; ++kc) {
      const int kb = kc * 32;
      __syncthreads();
      Hs[hkk][hr] = H[(size_t)(hb + hr) * DIM + kb + hkk] * hrn;
      {
        const float* src = Pk + (size_t)(pb + pr) * DIM + kb + pkk;
        float4 v0 = *(const float4*)(src);
        float4 v1 = *(const float4*)(src + 4);
        float4 v2 = *(const float4*)(src + 8);
        float4 v3 = *(const float4*)(src + 12);
        Ps[pkk +  0][pr] = v0.x * prn;  Ps[pkk +  1][pr] = v0.y * prn;
        Ps[pkk +  2][pr] = v0.z * prn;  Ps[pkk +  3][pr] = v0.w * prn;
        Ps[pkk +  4][pr] = v1.x * prn;  Ps[pkk +  5][pr] = v1.y * prn;
        Ps[pkk +  6][pr] = v1.z * prn;  Ps[pkk +  7][pr] = v1.w * prn;
        Ps[pkk +  8][pr] = v2.x * prn;  Ps[pkk +  9][pr] = v2.y * prn;
        Ps[pkk + 10][pr] = v2.z * prn;  Ps[pkk + 11][pr] = v2.w * prn;
        Ps[pkk + 12][pr] = v3.x * prn;  Ps[pkk + 13][pr] = v3.y * prn;
        Ps[pkk + 14][pr] = v3.z * prn;  Ps[pkk + 15][pr] = v3.w * prn;
      }
      __syncthreads();
#pragma unroll
      for (int k = 0; k < 32; ++k) {
        float2 a = *(const float2*)&Hs[k][2 * ry];
        float2 b = *(const float2*)&Ps[k][2 * tx];
        acc[0][0] += a.x * b.x; acc[0][1] += a.x * b.y;
        acc[1][0] += a.y * b.x; acc[1][1] += a.y * b.y;
      }
    }
    const int lab0 = labels[pb + 2 * tx];
    const int lab1 = labels[pb + 2 * tx + 1];
#pragma unroll
    for (int rr = 0; rr < 2; ++rr) {
      float l0 = acc[rr][0] / 0.07f;
      float l1 = acc[rr][1] / 0.07f;
      float tm = fmaxf(l0, l1);
#pragma unroll
      for (int off = 32; off; off >>= 1) tm = fmaxf(tm, __shfl_xor(tm, off));
      float mn = fmaxf(m[rr], tm);
      float sc = expf(m[rr] - mn);
      const int row = 2 * ry + rr;
#pragma unroll
      for (int qq = 0; qq < 4; ++qq) accc[row][tx + 64 * qq] *= sc;
      float e0 = expf(l0 - mn);
      float e1 = expf(l1 - mn);
      float es = e0 + e1;
#pragma unroll
      for (int off = 32; off; off >>= 1) es += __shfl_xor(es, off);
      ssum[rr] = ssum[rr] * sc + es;
      m[rr] = mn;
      atomicAdd(&accc[row][lab0], e0);
      atomicAdd(&accc[row][lab1], e1);
    }
  }
#pragma unroll
  for (int rr = 0; rr < 2; ++rr) {
    const int row = 2 * ry + rr;
    float inv = 1.0f / ssum[rr];
#pragma unroll
    for (int qq = 0; qq < 4; ++qq) {
      outp[(size_t)(hb + row) * C_CLS + tx + 64 * qq] = accc[row][tx + 64 * qq] * inv;
    }
  }
}

// ---------------------------------------------------------------------------
extern "C" void kernel_launch(void* const* d_in, const int* in_sizes, int n_in,
                              void* d_out, int out_size, void* d_ws, size_t ws_size,
                              hipStream_t stream) {
  (void)in_sizes; (void)n_in; (void)out_size;
  const float* F      = (const float*)d_in[0];
  const float* H      = (const float*)d_in[1];
  const float* Pk     = (const float*)d_in[2];
  const int*   labels = (const int*)d_in[3];
  float* out = (float*)d_out;

  // ws layout: norms(114688B) | cand(2MB) | fnb bf16(12.6MB) | fn32(25.2MB)
  float* ws   = (float*)d_ws;
  float* nrmF = ws;                               // 8192
  float* rnF  = nrmF + N_FEAT;                    // 8192
  float* nrmH = rnF + N_FEAT;                     // 4096
  float* rnH  = nrmH + B_H;                       // 4096
  float* nrmP = rnH + B_H;                        // 2048
  float* rnP  = nrmP + P_PK;                      // 2048
  int*   cand = (int*)(rnP + P_PK);               // 8192*64
  unsigned short* fnb = (unsigned short*)(cand + N_FEAT * 64);
  float* fn32 = (float*)(fnb + (size_t)N_FEAT * DIM);
  const size_t need = (size_t)(fn32 - ws) * 4 + (size_t)N_FEAT * DIM * 4;
  const bool use_fn32 = ws_size >= need;

  norm64_kernel<<<N_FEAT / 4, 256, 0, stream>>>(F, nrmF, rnF, N_FEAT);
  norm64_kernel<<<B_H / 4,  256, 0, stream>>>(H, nrmH, rnH, B_H);
  norm64_kernel<<<P_PK / 4, 256, 0, stream>>>(Pk, nrmP, rnP, P_PK);

  tobf16_kernel<<<N_FEAT * DIM / (8 * 256), 256, 0, stream>>>(F, rnF, fnb);
  if (use_fn32) {
    tofn32_kernel<<<N_FEAT * DIM / (4 * 256), 256, 0, stream>>>(F, nrmF, fn32);
  }

  sim_topk_mfma<<<256, 512, 0, stream>>>(fnb, cand);

  if (use_fn32) {
    refine64_fn32<<<N_FEAT, 256, 0, stream>>>(fn32, cand,
        out + OUT_DENS_OFF, out + OUT_KNN_OFF);
  } else {
    refine64_div<<<N_FEAT, 256, 0, stream>>>(F, nrmF, cand,
        out + OUT_DENS_OFF, out + OUT_KNN_OFF);
  }

  peak_kernel<<<N_FEAT / 256, 256, 0, stream>>>(out + OUT_DENS_OFF,
      out + OUT_KNN_OFF, out + OUT_MASK_OFF);

  preds_kernel<<<B_H / 8, 256, 0, stream>>>(H, Pk, labels, rnH, rnP, out);
}

// Round 11
// 1245.571 us; speedup vs baseline: 3.4892x; 1.1030x over previous
//
#include <hip/hip_runtime.h>
#include <math.h>

#define N_FEAT 8192
#define DIM    768
#define B_H    4096
#define P_PK   2048
#define C_CLS  256
#define KNN    20

// output layout (all float32, concatenated in reference return order)
#define OUT_DENS_OFF  (B_H * C_CLS)                 // 1048576
#define OUT_KNN_OFF   (OUT_DENS_OFF + N_FEAT)       // 1056768
#define OUT_MASK_OFF  (OUT_KNN_OFF + N_FEAT * KNN)  // 1220608

typedef __attribute__((ext_vector_type(8)))  short short8b;  // 8 bf16
typedef __attribute__((ext_vector_type(4)))  float f32x4;
typedef __attribute__((ext_vector_type(16))) float f32x16;

// ---------------------------------------------------------------------------
// Truth-rounded f32 row norm: n32 = fl32( sqrt_f64( sum_f64(x^2) ) ). [r8]
// ---------------------------------------------------------------------------
__global__ __launch_bounds__(256) void norm64_kernel(const float* __restrict__ X,
    float* __restrict__ nrm, float* __restrict__ rn, int rows) {
  int w    = (int)((blockIdx.x * blockDim.x + threadIdx.x) >> 6);
  int lane = threadIdx.x & 63;
  if (w >= rows) return;
  const float* x = X + (size_t)w * DIM;
  double s = 0.0;
#pragma unroll
  for (int k = 0; k < 12; ++k) {
    float v = x[lane + 64 * k];
    s += (double)v * (double)v;
  }
#pragma unroll
  for (int off = 32; off; off >>= 1) s += __shfl_xor(s, off);
  if (lane == 0) {
    float n32 = (float)sqrt(s);
    nrm[w] = n32;
    rn[w]  = 1.0f / n32;
  }
}

__device__ inline unsigned short f2bf(float x) {
  unsigned u = __float_as_uint(x);
  return (unsigned short)((u + 0x7fffu + ((u >> 16) & 1u)) >> 16);
}
__device__ inline float bf2f(unsigned short h) {
  return __uint_as_float(((unsigned)h) << 16);
}

// ---------------------------------------------------------------------------
// x*rn -> bf16 (RNE) single  (candidate GEMM input; also pn for preds)
// ---------------------------------------------------------------------------
__global__ __launch_bounds__(256) void tobf16_kernel(const float* __restrict__ F,
    const float* __restrict__ rn, unsigned short* __restrict__ fnb) {
  int gid = (blockIdx.x * 256 + threadIdx.x) * 8;
  int row = gid / DIM;
  float s = rn[row];
  float4 v0 = *(const float4*)(F + gid);
  float4 v1 = *(const float4*)(F + gid + 4);
  uint4 o;
  o.x = (unsigned)f2bf(v0.x * s) | ((unsigned)f2bf(v0.y * s) << 16);
  o.y = (unsigned)f2bf(v0.z * s) | ((unsigned)f2bf(v0.w * s) << 16);
  o.z = (unsigned)f2bf(v1.x * s) | ((unsigned)f2bf(v1.y * s) << 16);
  o.w = (unsigned)f2bf(v1.z * s) | ((unsigned)f2bf(v1.w * s) << 16);
  *(uint4*)(fnb + gid) = o;
}

// ---------------------------------------------------------------------------
// x*rn -> bf16 hi + bf16 lo (2-term split; residual ~2^-18) for hn
// ---------------------------------------------------------------------------
__global__ __launch_bounds__(256) void split_kernel(const float* __restrict__ X,
    const float* __restrict__ rn, unsigned short* __restrict__ hi,
    unsigned short* __restrict__ lo) {
  int gid = (blockIdx.x * 256 + threadIdx.x) * 8;
  int row = gid / DIM;
  float s = rn[row];
  float4 v0 = *(const float4*)(X + gid);
  float4 v1 = *(const float4*)(X + gid + 4);
  float x[8] = {v0.x * s, v0.y * s, v0.z * s, v0.w * s,
                v1.x * s, v1.y * s, v1.z * s, v1.w * s};
  unsigned short h[8], l[8];
#pragma unroll
  for (int i = 0; i < 8; ++i) {
    h[i] = f2bf(x[i]);
    l[i] = f2bf(x[i] - bf2f(h[i]));
  }
  uint4 oh, ol;
  oh.x = h[0] | ((unsigned)h[1] << 16); oh.y = h[2] | ((unsigned)h[3] << 16);
  oh.z = h[4] | ((unsigned)h[5] << 16); oh.w = h[6] | ((unsigned)h[7] << 16);
  ol.x = l[0] | ((unsigned)l[1] << 16); ol.y = l[2] | ((unsigned)l[3] << 16);
  ol.z = l[4] | ((unsigned)l[5] << 16); ol.w = l[6] | ((unsigned)l[7] << 16);
  *(uint4*)(hi + gid) = oh;
  *(uint4*)(lo + gid) = ol;
}

// ---------------------------------------------------------------------------
// fn32 = F / n32 — exact IEEE f32 quotients, materialized ONCE (refine path)
// ---------------------------------------------------------------------------
__global__ __launch_bounds__(256) void tofn32_kernel(const float* __restrict__ F,
    const float* __restrict__ nrm, float* __restrict__ fn32) {
#pragma clang fp contract(off)
  int gid = (blockIdx.x * 256 + threadIdx.x) * 4;
  int row = gid / DIM;
  float ni = nrm[row];
  float4 v = *(const float4*)(F + gid);
  v.x = v.x / ni; v.y = v.y / ni; v.z = v.z / ni; v.w = v.w / ni;
  *(float4*)(fn32 + gid) = v;
}

// ---------------------------------------------------------------------------
// bf16 32x32x16-MFMA candidate GEMM + register-list top-32 selection. [r10]
// ---------------------------------------------------------------------------
__global__ __launch_bounds__(512, 2) void sim_topk_mfma(
    const unsigned short* __restrict__ fnb, int* __restrict__ cand) {
  __shared__ __align__(16) uint4 Bs[2][128 * 17];
  __shared__ __align__(16) float simb[64][130];

  const int t  = threadIdx.x;
  const int l  = t & 63;
  const int w  = t >> 6;
  const int wr = w >> 2;
  const int wc = w & 3;
  const int rg = blockIdx.x >> 1;
  const int hg = blockIdx.x & 1;
  const int ib = rg * 64;
  const int jb0 = hg * 4096;

  const int lc = l & 31;
  const int lh = l >> 5;
  const int bsw = 4 * (lc & 3);

  const int scol = t >> 2;
  const int sq   = t & 3;
  const int wsw  = sq ^ (scol & 3);

  short8b a[48];
  {
    const unsigned short* ap = fnb + (size_t)(ib + wr * 32 + lc) * DIM + lh * 8;
#pragma unroll
    for (int kc = 0; kc < 48; ++kc) a[kc] = *(const short8b*)(ap + kc * 16);
  }

  const int h = l >> 5;
  const int q = l & 31;
  float lv[4], cmv[4];
  int   li[4];
#pragma unroll
  for (int p = 0; p < 4; ++p) { lv[p] = -3e38f; li[p] = 0; cmv[p] = -3e38f; }

  uint4 v0, v1, v2, v3;
  {
    const unsigned short* gb = fnb + (size_t)(jb0 + scol) * DIM + sq * 32;
    v0 = *(const uint4*)(gb);
    v1 = *(const uint4*)(gb + 8);
    v2 = *(const uint4*)(gb + 16);
    v3 = *(const uint4*)(gb + 24);
  }
  int cur = 0;

#pragma unroll 1
  for (int ct = 0; ct < 32; ++ct) {
    f32x16 acc;
#pragma unroll
    for (int i = 0; i < 16; ++i) acc[i] = 0.f;

#pragma unroll
    for (int kq = 0; kq < 6; ++kq) {
      {
        uint4* bd = &Bs[cur][scol * 17 + 4 * wsw];
        bd[0] = v0; bd[1] = v1; bd[2] = v2; bd[3] = v3;
      }
      __syncthreads();
      if (!(ct == 31 && kq == 5)) {
        const int nct = (kq == 5) ? ct + 1 : ct;
        const int nkq = (kq == 5) ? 0 : kq + 1;
        const unsigned short* gb =
            fnb + (size_t)(jb0 + nct * 128 + scol) * DIM + nkq * 128 + sq * 32;
        v0 = *(const uint4*)(gb);
        v1 = *(const uint4*)(gb + 8);
        v2 = *(const uint4*)(gb + 16);
        v3 = *(const uint4*)(gb + 24);
      }
#pragma unroll
      for (int s = 0; s < 8; ++s) {
        const int slot = (2 * s + lh) ^ bsw;
        const short8b b = *(const short8b*)&Bs[cur][(wc * 32 + lc) * 17 + slot];
        acc = __builtin_amdgcn_mfma_f32_32x32x16_bf16(a[kq * 8 + s], b, acc, 0, 0, 0);
      }
      cur ^= 1;
    }

#pragma unroll
    for (int reg = 0; reg < 16; ++reg) {
      simb[wr * 32 + (reg & 3) + 8 * (reg >> 2) + 4 * lh][wc * 32 + lc] = acc[reg];
    }
    __syncthreads();

    const int jbct = jb0 + ct * 128;
#pragma unroll
    for (int p = 0; p < 4; ++p) {
      const int r  = w * 8 + 2 * p + h;
      const int ig = ib + r;
#pragma unroll
      for (int s = 0; s < 4; ++s) {
        float v  = simb[r][32 * s + q];
        int   jj = jbct + 32 * s + q;
        bool pred = (v > cmv[p]) && (jj != ig);
        unsigned long long bm = __ballot(pred);
        unsigned hm = (unsigned)(bm >> (h * 32));
        while (hm) {
          const int lb = __ffs(hm) - 1;
          hm &= hm - 1;
          const float bv = __shfl(v,  h * 32 + lb);
          const int   bj = __shfl(jj, h * 32 + lb);
          if (bv > cmv[p]) {
            unsigned em = (unsigned)(__ballot(lv[p] == cmv[p]) >> (h * 32));
            if (q == __ffs(em) - 1) { lv[p] = bv; li[p] = bj; }
            float ov = lv[p];
#pragma unroll
            for (int d = 1; d <= 16; d <<= 1) ov = fminf(ov, __shfl_xor(ov, d));
            cmv[p] = ov;
          }
        }
      }
    }
  }

#pragma unroll
  for (int p = 0; p < 4; ++p) {
    const int ig = ib + w * 8 + 2 * p + h;
    cand[(size_t)ig * 64 + hg * 32 + q] = li[p];
  }
}

// ---------------------------------------------------------------------------
// Exact re-rank (fn32 path) [r10-verified]
// ---------------------------------------------------------------------------
__global__ __launch_bounds__(256) void refine64_fn32(const float* __restrict__ fn32,
    const int* __restrict__ cand, float* __restrict__ dens, float* __restrict__ knnf) {
#pragma clang fp contract(off)
  const int i = blockIdx.x;
  const int t = threadIdx.x;
  const int l = t & 63;
  const int w = t >> 6;
  __shared__ __align__(16) float fni[DIM];
  __shared__ float s32v[64];
  __shared__ int   vidx[64];
  __shared__ float ssorted[KNN];

  const float* fni_g = fn32 + (size_t)i * DIM;
  for (int d = t; d < DIM; d += 256) fni[d] = fni_g[d];
  if (t < 64) vidx[t] = cand[(size_t)i * 64 + t];
  __syncthreads();

  for (int c = w * 16; c < w * 16 + 16; ++c) {
    const int j = vidx[c];
    const float* fj = fn32 + (size_t)j * DIM;
    double s = 0.0;
#pragma unroll
    for (int k2 = 0; k2 < 12; ++k2) {
      s += (double)fni[l + 64 * k2] * (double)fj[l + 64 * k2];
    }
#pragma unroll
    for (int off = 32; off; off >>= 1) s += __shfl_xor(s, off);
    if (l == 0) s32v[c] = (float)s;
  }
  __syncthreads();

  if (t < 64) {
    const float v = s32v[t];
    const int   j = vidx[t];
    int rank = 0;
    for (int k = 0; k < 64; ++k) {
      float vk = s32v[k]; int jk = vidx[k];
      rank += (vk > v || (vk == v && jk > j)) ? 1 : 0;
    }
    if (rank < KNN) {
      knnf[(size_t)i * KNN + rank] = (float)j;
      ssorted[rank] = v;
    }
  }
  __syncthreads();

  if (t == 0) {
    float rr[8];
#pragma unroll
    for (int u = 0; u < 8; ++u) rr[u] = ssorted[u];
#pragma unroll
    for (int u = 0; u < 8; ++u) rr[u] = rr[u] + ssorted[8 + u];
    float res = ((rr[0] + rr[1]) + (rr[2] + rr[3])) + ((rr[4] + rr[5]) + (rr[6] + rr[7]));
    res = res + ssorted[16];
    res = res + ssorted[17];
    res = res + ssorted[18];
    res = res + ssorted[19];
    dens[i] = res / 20.0f;
  }
}

// ---------------------------------------------------------------------------
// Fallback refine (divisions in-kernel) if ws too small [r9-verified]
// ---------------------------------------------------------------------------
__global__ __launch_bounds__(256) void refine64_div(const float* __restrict__ F,
    const float* __restrict__ nrm, const int* __restrict__ cand,
    float* __restrict__ dens, float* __restrict__ knnf) {
#pragma clang fp contract(off)
  const int i = blockIdx.x;
  const int t = threadIdx.x;
  const int l = t & 63;
  const int w = t >> 6;
  __shared__ __align__(16) float fni[DIM];
  __shared__ float s32v[64];
  __shared__ int   vidx[64];
  __shared__ float ssorted[KNN];

  const float ni = nrm[i];
  for (int d = t; d < DIM; d += 256) fni[d] = F[(size_t)i * DIM + d] / ni;
  if (t < 64) vidx[t] = cand[(size_t)i * 64 + t];
  __syncthreads();

  for (int c = w * 16; c < w * 16 + 16; ++c) {
    const int j = vidx[c];
    const float* fj = F + (size_t)j * DIM;
    const float nj = nrm[j];
    double s = 0.0;
#pragma unroll
    for (int k2 = 0; k2 < 12; ++k2) {
      float fjn = fj[l + 64 * k2] / nj;
      s += (double)fni[l + 64 * k2] * (double)fjn;
    }
#pragma unroll
    for (int off = 32; off; off >>= 1) s += __shfl_xor(s, off);
    if (l == 0) s32v[c] = (float)s;
  }
  __syncthreads();

  if (t < 64) {
    const float v = s32v[t];
    const int   j = vidx[t];
    int rank = 0;
    for (int k = 0; k < 64; ++k) {
      float vk = s32v[k]; int jk = vidx[k];
      rank += (vk > v || (vk == v && jk > j)) ? 1 : 0;
    }
    if (rank < KNN) {
      knnf[(size_t)i * KNN + rank] = (float)j;
      ssorted[rank] = v;
    }
  }
  __syncthreads();

  if (t == 0) {
    float rr[8];
#pragma unroll
    for (int u = 0; u < 8; ++u) rr[u] = ssorted[u];
#pragma unroll
    for (int u = 0; u < 8; ++u) rr[u] = rr[u] + ssorted[8 + u];
    float res = ((rr[0] + rr[1]) + (rr[2] + rr[3])) + ((rr[4] + rr[5]) + (rr[6] + rr[7]));
    res = res + ssorted[16];
    res = res + ssorted[17];
    res = res + ssorted[18];
    res = res + ssorted[19];
    dens[i] = res / 20.0f;
  }
}

// ---------------------------------------------------------------------------
// peak_mask[i] = all(dens[i] > dens[knn[i][k]])  [r8]
// ---------------------------------------------------------------------------
__global__ __launch_bounds__(256) void peak_kernel(const float* __restrict__ dens,
    const float* __restrict__ knnf, float* __restrict__ mask) {
  int i = blockIdx.x * 256 + threadIdx.x;
  if (i >= N_FEAT) return;
  float di = dens[i];
  int ok = 1;
#pragma unroll
  for (int k = 0; k < KNN; ++k) {
    int j = (int)knnf[(size_t)i * KNN + k];
    ok &= (di > dens[j]) ? 1 : 0;
  }
  mask[i] = ok ? 1.0f : 0.0f;
}

// ---------------------------------------------------------------------------
// MFMA preds: logits = (hh+hl)·ph^T / tau  (A split bf16, B single bf16),
// fused online softmax + one-hot label scatter into LDS class accumulators.
// 256 blocks x 16 h-rows; 512 thr = 8 waves (wave w owns cols 16w of each
// 128-col tile; softmax rows 2w,2w+1). A in 192 VGPR for full K=768.
// B staged per 32-k chunk, stride-40-short LDS rows (<=2-way banks), r10
// prefetch-under-MFMA double-buffer.
// ---------------------------------------------------------------------------
__global__ __launch_bounds__(512) void preds_mfma(
    const unsigned short* __restrict__ hh, const unsigned short* __restrict__ hl,
    const unsigned short* __restrict__ ph, const int* __restrict__ labels,
    float* __restrict__ outp) {
  __shared__ __align__(16) unsigned short Bsh[2][128 * 40];  // 20.5 KB
  __shared__ __align__(16) float logit[16][132];             // 8.4 KB
  __shared__ float accc[16][C_CLS];                          // 16 KB
  __shared__ int   labs[P_PK];                               // 8 KB

  const int t  = threadIdx.x;
  const int l  = t & 63;
  const int w  = t >> 6;          // 0..7
  const int hb = blockIdx.x * 16;
  const int lr = l & 15;
  const int lk = l >> 4;

  // ---- A fragments (rows hb+lr, full K): hi + lo
  short8b Ah[24], Al[24];
  {
    const unsigned short* hp = hh + (size_t)(hb + lr) * DIM + lk * 8;
    const unsigned short* lp = hl + (size_t)(hb + lr) * DIM + lk * 8;
#pragma unroll
    for (int kc = 0; kc < 24; ++kc) {
      Ah[kc] = *(const short8b*)(hp + kc * 32);
      Al[kc] = *(const short8b*)(lp + kc * 32);
    }
  }

  for (int i = t; i < P_PK; i += 512) labs[i] = labels[i];
  for (int i = t; i < 16 * C_CLS; i += 512) ((float*)accc)[i] = 0.f;

  float m0 = -3e38f, m1 = -3e38f, s0 = 0.f, s1 = 0.f;

  // staging map: col = t>>2 (0..127), seg = t&3 (8 k each)
  const int scol = t >> 2;
  const int sseg = t & 3;

  // prologue prefetch (ct=0, kc=0)
  uint4 pv = *(const uint4*)(ph + (size_t)scol * DIM + sseg * 8);
  int cur = 0;
  __syncthreads();

#pragma unroll 1
  for (int ct = 0; ct < 16; ++ct) {
    f32x4 acc = {0.f, 0.f, 0.f, 0.f};

#pragma unroll 1
    for (int kc = 0; kc < 24; ++kc) {
      *(uint4*)&Bsh[cur][scol * 40 + sseg * 8] = pv;
      __syncthreads();
      if (!(ct == 15 && kc == 23)) {
        const int nct = (kc == 23) ? ct + 1 : ct;
        const int nkc = (kc == 23) ? 0 : kc + 1;
        pv = *(const uint4*)(ph + (size_t)(nct * 128 + scol) * DIM + nkc * 32 + sseg * 8);
      }
      const short8b b = *(const short8b*)&Bsh[cur][(16 * w + lr) * 40 + lk * 8];
      acc = __builtin_amdgcn_mfma_f32_16x16x32_bf16(Ah[kc], b, acc, 0, 0, 0);
      acc = __builtin_amdgcn_mfma_f32_16x16x32_bf16(Al[kc], b, acc, 0, 0, 0);
      cur ^= 1;
    }

    // spill logits (C/D: col=lane&15, row=4*(lane>>4)+reg), scaled by 1/tau
#pragma unroll
    for (int reg = 0; reg < 4; ++reg) {
      logit[lk * 4 + reg][16 * w + lr] = acc[reg] / 0.07f;
    }
    __syncthreads();

    // online softmax + scatter: wave w owns rows 2w, 2w+1
    const int pb = ct * 128;
    const int lab0 = labs[pb + l];
    const int lab1 = labs[pb + 64 + l];
#pragma unroll
    for (int rr = 0; rr < 2; ++rr) {
      const int r = 2 * w + rr;
      float v0 = logit[r][l];
      float v1 = logit[r][64 + l];
      float tm = fmaxf(v0, v1);
#pragma unroll
      for (int off = 32; off; off >>= 1) tm = fmaxf(tm, __shfl_xor(tm, off));
      float mo = rr ? m1 : m0;
      float mn = fmaxf(mo, tm);
      float sc = expf(mo - mn);
#pragma unroll
      for (int qq = 0; qq < 4; ++qq) accc[r][l + 64 * qq] *= sc;
      float e0 = expf(v0 - mn);
      float e1 = expf(v1 - mn);
      float es = e0 + e1;
#pragma unroll
      for (int off = 32; off; off >>= 1) es += __shfl_xor(es, off);
      if (rr) { s1 = s1 * sc + es; m1 = mn; }
      else    { s0 = s0 * sc + es; m0 = mn; }
      atomicAdd(&accc[r][lab0], e0);
      atomicAdd(&accc[r][lab1], e1);
    }
    __syncthreads();   // logit/accc settled before next tile's spill
  }

  // write normalized predictions: wave w rows 2w,2w+1
#pragma unroll
  for (int rr = 0; rr < 2; ++rr) {
    const int r = 2 * w + rr;
    const float inv = 1.0f / (rr ? s1 : s0);
#pragma unroll
    for (int qq = 0; qq < 4; ++qq) {
      outp[(size_t)(hb + r) * C_CLS + l + 64 * qq] = accc[r][l + 64 * qq] * inv;
    }
  }
}

// ---------------------------------------------------------------------------
// Fallback preds (f32 VALU) [r10-verified]
// ---------------------------------------------------------------------------
__global__ __launch_bounds__(256) void preds_kernel(const float* __restrict__ H,
    const float* __restrict__ Pk, const int* __restrict__ labels,
    const float* __restrict__ rnh, const float* __restrict__ rnp,
    float* __restrict__ outp) {
  __shared__ __align__(16) float Hs[32][12];
  __shared__ __align__(16) float Ps[32][130];
  __shared__ float accc[8][C_CLS];

  const int t  = threadIdx.x;
  const int hb = blockIdx.x * 8;
  const int tx = t & 63;
  const int ry = t >> 6;
  const int hr  = t >> 5;
  const int hkk = t & 31;
  const int pr  = t >> 1;
  const int pkk = (t & 1) * 16;
  const float hrn = rnh[hb + hr];

  for (int i = t; i < 8 * C_CLS; i += 256) ((float*)accc)[i] = 0.f;

  float m[2]    = {-3e38f, -3e38f};
  float ssum[2] = {0.f, 0.f};
  __syncthreads();

  for (int pt = 0; pt < 16; ++pt) {
    const int pb = pt * 128;
    const float prn = rnp[pb + pr];
    float acc[2][2] = {{0.f, 0.f}, {0.f, 0.f}};

    for (int kc = 0; kc < 24; ++kc) {
      const int kb = kc * 32;
      __syncthreads();
      Hs[hkk][hr] = H[(size_t)(hb + hr) * DIM + kb + hkk] * hrn;
      {
        const float* src = Pk + (size_t)(pb + pr) * DIM + kb + pkk;
        float4 v0 = *(const float4*)(src);
        float4 v1 = *(const float4*)(src + 4);
        float4 v2 = *(const float4*)(src + 8);
        float4 v3 = *(const float4*)(src + 12);
        Ps[pkk +  0][pr] = v0.x * prn;  Ps[pkk +  1][pr] = v0.y * prn;
        Ps[pkk +  2][pr] = v0.z * prn;  Ps[pkk +  3][pr] = v0.w * prn;
        Ps[pkk +  4][pr] = v1.x * prn;  Ps[pkk +  5][pr] = v1.y * prn;
        Ps[pkk +  6][pr] = v1.z * prn;  Ps[pkk +  7][pr] = v1.w * prn;
        Ps[pkk +  8][pr] = v2.x * prn;  Ps[pkk +  9][pr] = v2.y * prn;
        Ps[pkk + 10][pr] = v2.z * prn;  Ps[pkk + 11][pr] = v2.w * prn;
        Ps[pkk + 12][pr] = v3.x * prn;  Ps[pkk + 13][pr] = v3.y * prn;
        Ps[pkk + 14][pr] = v3.z * prn;  Ps[pkk + 15][pr] = v3.w * prn;
      }
      __syncthreads();
#pragma unroll
      for (int k = 0; k < 32; ++k) {
        float2 a = *(const float2*)&Hs[k][2 * ry];
        float2 b = *(const float2*)&Ps[k][2 * tx];
        acc[0][0] += a.x * b.x; acc[0][1] += a.x * b.y;
        acc[1][0] += a.y * b.x; acc[1][1] += a.y * b.y;
      }
    }
    const int lab0 = labels[pb + 2 * tx];
    const int lab1 = labels[pb + 2 * tx + 1];
#pragma unroll
    for (int rr = 0; rr < 2; ++rr) {
      float l0 = acc[rr][0] / 0.07f;
      float l1 = acc[rr][1] / 0.07f;
      float tm = fmaxf(l0, l1);
#pragma unroll
      for (int off = 32; off; off >>= 1) tm = fmaxf(tm, __shfl_xor(tm, off));
      float mn = fmaxf(m[rr], tm);
      float sc = expf(m[rr] - mn);
      const int row = 2 * ry + rr;
#pragma unroll
      for (int qq = 0; qq < 4; ++qq) accc[row][tx + 64 * qq] *= sc;
      float e0 = expf(l0 - mn);
      float e1 = expf(l1 - mn);
      float es = e0 + e1;
#pragma unroll
      for (int off = 32; off; off >>= 1) es += __shfl_xor(es, off);
      ssum[rr] = ssum[rr] * sc + es;
      m[rr] = mn;
      atomicAdd(&accc[row][lab0], e0);
      atomicAdd(&accc[row][lab1], e1);
    }
  }
#pragma unroll
  for (int rr = 0; rr < 2; ++rr) {
    const int row = 2 * ry + rr;
    float inv = 1.0f / ssum[rr];
#pragma unroll
    for (int qq = 0; qq < 4; ++qq) {
      outp[(size_t)(hb + row) * C_CLS + tx + 64 * qq] = accc[row][tx + 64 * qq] * inv;
    }
  }
}

// ---------------------------------------------------------------------------
extern "C" void kernel_launch(void* const* d_in, const int* in_sizes, int n_in,
                              void* d_out, int out_size, void* d_ws, size_t ws_size,
                              hipStream_t stream) {
  (void)in_sizes; (void)n_in; (void)out_size;
  const float* F      = (const float*)d_in[0];
  const float* H      = (const float*)d_in[1];
  const float* Pk     = (const float*)d_in[2];
  const int*   labels = (const int*)d_in[3];
  float* out = (float*)d_out;

  // ws layout: norms | cand | fnb | hh | hl | ph | fn32
  float* ws   = (float*)d_ws;
  float* nrmF = ws;                               // 8192
  float* rnF  = nrmF + N_FEAT;                    // 8192
  float* nrmH = rnF + N_FEAT;                     // 4096
  float* rnH  = nrmH + B_H;                       // 4096
  float* nrmP = rnH + B_H;                        // 2048
  float* rnP  = nrmP + P_PK;                      // 2048
  int*   cand = (int*)(rnP + P_PK);               // 8192*64
  unsigned short* fnb = (unsigned short*)(cand + N_FEAT * 64);   // 12.6 MB
  unsigned short* hhb = fnb + (size_t)N_FEAT * DIM;              // 6.3 MB
  unsigned short* hlb = hhb + (size_t)B_H * DIM;                 // 6.3 MB
  unsigned short* phb = hlb + (size_t)B_H * DIM;                 // 3.1 MB
  float* fn32 = (float*)(phb + (size_t)P_PK * DIM);              // 25.2 MB

  const size_t base = (size_t)((char*)phb - (char*)ws);
  const size_t need_preds = base + (size_t)P_PK * DIM * 2;
  const size_t need_fn32  = need_preds + (size_t)N_FEAT * DIM * 4;
  const bool use_preds = ws_size >= need_preds;
  const bool use_fn32  = ws_size >= need_fn32;

  norm64_kernel<<<N_FEAT / 4, 256, 0, stream>>>(F, nrmF, rnF, N_FEAT);
  norm64_kernel<<<B_H / 4,  256, 0, stream>>>(H, nrmH, rnH, B_H);
  norm64_kernel<<<P_PK / 4, 256, 0, stream>>>(Pk, nrmP, rnP, P_PK);

  tobf16_kernel<<<N_FEAT * DIM / (8 * 256), 256, 0, stream>>>(F, rnF, fnb);
  if (use_preds) {
    split_kernel<<<B_H * DIM / (8 * 256), 256, 0, stream>>>(H, rnH, hhb, hlb);
    tobf16_kernel<<<P_PK * DIM / (8 * 256), 256, 0, stream>>>(Pk, rnP, phb);
  }
  if (use_fn32) {
    tofn32_kernel<<<N_FEAT * DIM / (4 * 256), 256, 0, stream>>>(F, nrmF, fn32);
  }

  sim_topk_mfma<<<256, 512, 0, stream>>>(fnb, cand);

  if (use_fn32) {
    refine64_fn32<<<N_FEAT, 256, 0, stream>>>(fn32, cand,
        out + OUT_DENS_OFF, out + OUT_KNN_OFF);
  } else {
    refine64_div<<<N_FEAT, 256, 0, stream>>>(F, nrmF, cand,
        out + OUT_DENS_OFF, out + OUT_KNN_OFF);
  }

  peak_kernel<<<N_FEAT / 256, 256, 0, stream>>>(out + OUT_DENS_OFF,
      out + OUT_KNN_OFF, out + OUT_MASK_OFF);

  if (use_preds) {
    preds_mfma<<<B_H / 16, 512, 0, stream>>>(hhb, hlb, phb, labels, out);
  } else {
    preds_kernel<<<B_H / 8, 256, 0, stream>>>(H, Pk, labels, rnH, rnP, out);
  }
}